// Round 1
// baseline (1071.754 us; speedup 1.0000x reference)
//
#include <hip/hip_runtime.h>
#include <hip/hip_bf16.h>

// SlidingFFAgent: fused 5-layer MLP + sliding window, bf16 MFMA pipeline.
// BS=32 TS=256 NA=16 OS=512 HID=1024 D=128 W=8 OUT=512 DEC=512 NACT=30
// ROWS = 131072. All GEMMs via v_mfma_f32_16x16x32_bf16.
// Fragment maps (m89-verified): A: row=l&15, k=(l>>4)*8+j ; B: col=l&15, same k ;
// D: col=l&15, row=(l>>4)*4+reg.

#define DEVI __device__ __forceinline__

typedef float f32x4 __attribute__((ext_vector_type(4)));
typedef short s16x8 __attribute__((ext_vector_type(8)));

#define ROWS 131072
#define SEQ_T 263

// packed weight offsets (in shorts)
#define W2P_OFF 524288
#define W3P_OFF 655360
#define W4P_OFF 1179648
#define W5P_OFF 1441792
#define WP_TOTAL 1458176

#define SEQ_BYTE_OFF 2916352
#define BIG_BYTE_OFF 37388288   // Apack (enc input frags), later aliased as h3p

DEVI short f2bf(float f) {
  union { __hip_bfloat16 h; short s; } u;
  u.h = __float2bfloat16(f);
  return u.s;
}
DEVI float bf2f(short s) {
  union { __hip_bfloat16 h; short s; } u;
  u.s = s;
  return __bfloat162float(u.h);
}

DEVI f32x4 MFMA(s16x8 a, s16x8 b, f32x4 c) {
  return __builtin_amdgcn_mfma_f32_16x16x32_bf16(a, b, c, 0, 0, 0);
}

// ---------------- weight packing: W[k][n] f32 -> B-frag-packed bf16 ----------------
// dest elem index: ((n0*K32 + k0)*64 + lane)*8 + j ; lane = ((k>>3)&3)<<4 | (n&15)
__global__ __launch_bounds__(256) void pack_w_kernel(
    const float* __restrict__ w1, const float* __restrict__ w2,
    const float* __restrict__ w3, const float* __restrict__ w4,
    const float* __restrict__ w5, short* __restrict__ wp)
{
  int idx = blockIdx.x * 256 + threadIdx.x;
  const float* src; int sh, Nsrc, local;
  if (idx < W2P_OFF)      { src = w1; sh = 4; Nsrc = 1024; local = idx; }
  else if (idx < W3P_OFF) { src = w2; sh = 5; Nsrc = 128;  local = idx - W2P_OFF; }
  else if (idx < W4P_OFF) { src = w3; sh = 5; Nsrc = 512;  local = idx - W3P_OFF; }
  else if (idx < W5P_OFF) { src = w4; sh = 4; Nsrc = 512;  local = idx - W4P_OFF; }
  else                    { src = w5; sh = 4; Nsrc = 30;   local = idx - W5P_OFF; }
  int j    = local & 7;
  int lane = (local >> 3) & 63;
  int rest = local >> 9;
  int k0   = rest & ((1 << sh) - 1);
  int n0   = rest >> sh;
  int k = (k0 << 5) + ((lane >> 4) << 3) + j;
  int n = (n0 << 4) + (lane & 15);
  float v = (n < Nsrc) ? src[k * Nsrc + n] : 0.f;
  wp[idx] = f2bf(v);
}

// ---------------- inputs f32 -> A-frag-packed bf16 ----------------
__global__ __launch_bounds__(256) void pack_inp_kernel(
    const float* __restrict__ inp, short* __restrict__ ap)
{
  int c = blockIdx.x * 256 + threadIdx.x;     // 16B chunk index, 8,388,608 total
  int l  = c & 63;
  int k0 = (c >> 6) & 15;
  int mt = c >> 10;
  int row = (mt << 4) | (l & 15);
  int kb  = (k0 << 5) | ((l >> 4) << 3);
  const float* s = inp + row * 512 + kb;
  f32x4 v0 = *(const f32x4*)s;
  f32x4 v1 = *(const f32x4*)(s + 4);
  s16x8 o;
  o[0]=f2bf(v0[0]); o[1]=f2bf(v0[1]); o[2]=f2bf(v0[2]); o[3]=f2bf(v0[3]);
  o[4]=f2bf(v1[0]); o[5]=f2bf(v1[1]); o[6]=f2bf(v1[2]); o[7]=f2bf(v1[3]);
  *(s16x8*)(ap + (long)c * 8) = o;
}

// ---------------- hidden_state -> seq frames 0..6 (pre-swizzled) ----------------
// seq storage: logical (ba,f,d) stored at slot' = (d>>3) ^ (f&7) within frame.
__global__ __launch_bounds__(256) void hid_copy_kernel(
    const float* __restrict__ hid, short* __restrict__ seqp)
{
  int idx = blockIdx.x * 256 + threadIdx.x;   // 458752 total
  int d  = idx & 127;
  int r  = idx >> 7;
  int i  = r % 7;
  int ba = r / 7;
  int s  = (d >> 3) ^ i;  // f = i, f&7 = i
  seqp[(ba * SEQ_T + i) * 128 + s * 8 + (d & 7)] = f2bf(hid[idx]);
}

// ---------------- encoder: x2 = relu(relu(inp@w1+b1)@w2+b2) -> seq ----------------
__global__ __launch_bounds__(512, 4) void enc_kernel(
    const short* __restrict__ ap, const short* __restrict__ w1p,
    const float* __restrict__ b1, const short* __restrict__ w2p,
    const float* __restrict__ b2, short* __restrict__ seqp)
{
  __shared__ short h1s[32768] __attribute__((aligned(16)));  // 64KB
  const int tid = threadIdx.x;
  const int lane = tid & 63, wid = tid >> 6;
  const int wm = wid >> 2, wn = wid & 3;
  const int l15 = lane & 15, lg = lane >> 4;
  const int rb = blockIdx.x << 6;

  f32x4 z = {0.f, 0.f, 0.f, 0.f};
  f32x4 acc2[2][2] = {{z, z}, {z, z}};
  const short* aB0 = ap + ((rb >> 4) + wm * 2) * 8192 + lane * 8;
  const short* aB1 = aB0 + 8192;

  for (int nh = 0; nh < 2; ++nh) {
    f32x4 acc[2][8];
    #pragma unroll
    for (int i = 0; i < 2; ++i)
      #pragma unroll
      for (int j = 0; j < 8; ++j) acc[i][j] = z;

    const short* bB = w1p + (nh * 32 + wn * 8) * 8192 + lane * 8;
    #pragma unroll 2
    for (int k0 = 0; k0 < 16; ++k0) {
      s16x8 a0 = *(const s16x8*)(aB0 + k0 * 512);
      s16x8 a1 = *(const s16x8*)(aB1 + k0 * 512);
      #pragma unroll
      for (int nf = 0; nf < 8; ++nf) {
        s16x8 bb = *(const s16x8*)(bB + nf * 8192 + k0 * 512);
        acc[0][nf] = MFMA(a0, bb, acc[0][nf]);
        acc[1][nf] = MFMA(a1, bb, acc[1][nf]);
      }
    }
    if (nh == 1) __syncthreads();  // stage2 of half 0 done reading h1s
    // write h1 half (relu+b1) into swizzled LDS
    #pragma unroll
    for (int mf = 0; mf < 2; ++mf)
      #pragma unroll
      for (int nf = 0; nf < 8; ++nf) {
        int col = wn * 128 + nf * 16 + l15;
        float bias = b1[nh * 512 + col];
        #pragma unroll
        for (int rr = 0; rr < 4; ++rr) {
          int row = wm * 32 + mf * 16 + lg * 4 + rr;
          float v = fmaxf(acc[mf][nf][rr] + bias, 0.f);
          int by = ((row << 10) + (col << 1)) ^ ((row & 7) << 4);
          h1s[by >> 1] = f2bf(v);
        }
      }
    __syncthreads();
    // stage 2: x2 += h1half @ w2[khalf]
    #pragma unroll 2
    for (int kk = 0; kk < 16; ++kk) {
      int row0 = wm * 32 + l15;
      int row1 = row0 + 16;
      int by0 = ((row0 << 10) + (kk << 6) + (lg << 4)) ^ ((row0 & 7) << 4);
      int by1 = ((row1 << 10) + (kk << 6) + (lg << 4)) ^ ((row1 & 7) << 4);
      s16x8 a0 = *(const s16x8*)((const char*)h1s + by0);
      s16x8 a1 = *(const s16x8*)((const char*)h1s + by1);
      #pragma unroll
      for (int nf = 0; nf < 2; ++nf) {
        s16x8 bb = *(const s16x8*)(w2p + (((wn * 2 + nf) * 32 + nh * 16 + kk) * 64 + lane) * 8);
        acc2[0][nf] = MFMA(a0, bb, acc2[0][nf]);
        acc2[1][nf] = MFMA(a1, bb, acc2[1][nf]);
      }
    }
  }
  // epilogue: repack x2 via LDS, vector store to pre-swizzled seq
  __syncthreads();
  #pragma unroll
  for (int mf = 0; mf < 2; ++mf)
    #pragma unroll
    for (int nf = 0; nf < 2; ++nf) {
      int col = wn * 32 + nf * 16 + l15;
      float bias = b2[col];
      #pragma unroll
      for (int rr = 0; rr < 4; ++rr) {
        int row = wm * 32 + mf * 16 + lg * 4 + rr;
        float v = fmaxf(acc2[mf][nf][rr] + bias, 0.f);
        h1s[row * 128 + col] = f2bf(v);
      }
    }
  __syncthreads();
  #pragma unroll
  for (int it = 0; it < 2; ++it) {
    int c = it * 512 + tid;
    int row = c >> 4, s = c & 15;
    int R = rb + row;
    int b = R >> 12, t = (R >> 4) & 255, a2 = R & 15;
    int f = t + 7;
    int dst = ((b * 16 + a2) * SEQ_T + f) * 128 + ((s ^ (f & 7)) * 8);
    *(s16x8*)(seqp + dst) = *(const s16x8*)&h1s[row * 128 + s * 8];
  }
}

// ---------------- sliding-window GEMM: h3 = relu(wins@w3+b3) -> frag-packed ----------------
__global__ __launch_bounds__(1024, 4) void win_kernel(
    const short* __restrict__ seqp, const short* __restrict__ w3p,
    const float* __restrict__ b3, short* __restrict__ h3p)
{
  __shared__ short sh[17280] __attribute__((aligned(16)));  // 135 frames staged / reused as repack buf
  const int tid = threadIdx.x;
  const int lane = tid & 63, wid = tid >> 6;
  const int wm = wid >> 2, wn = wid & 3;
  const int l15 = lane & 15, lg = lane >> 4;
  const int bid = blockIdx.x;
  const int th = bid & 1, ba = bid >> 1;
  const int b = ba >> 4, a = ba & 15;
  const int t0 = th << 7;

  // stage 135 frames (pre-swizzled global -> linear LDS copy keeps swizzle)
  const short* gsrc = seqp + (ba * SEQ_T + t0) * 128;
  #pragma unroll
  for (int i = 0; i < 3; ++i) {
    int c = i * 1024 + tid;
    if (c < 2160) *(s16x8*)&sh[c * 8] = *(const s16x8*)(gsrc + c * 8);
  }
  __syncthreads();

  f32x4 z = {0.f, 0.f, 0.f, 0.f};
  f32x4 acc[2][8];
  #pragma unroll
  for (int i = 0; i < 2; ++i)
    #pragma unroll
    for (int j = 0; j < 8; ++j) acc[i][j] = z;

  #pragma unroll 2
  for (int kc = 0; kc < 32; ++kc) {
    int w = kc >> 2;
    int dby = ((kc & 3) << 6) + (lg << 4);
    int f0 = wm * 32 + l15 + w;
    int f1 = f0 + 16;
    s16x8 a0 = *(const s16x8*)((const char*)sh + (((f0 << 8) + dby) ^ ((f0 & 7) << 4)));
    s16x8 a1 = *(const s16x8*)((const char*)sh + (((f1 << 8) + dby) ^ ((f1 & 7) << 4)));
    #pragma unroll
    for (int nf = 0; nf < 8; ++nf) {
      s16x8 bb = *(const s16x8*)(w3p + ((((wn * 8 + nf) * 32 + kc) * 64 + lane) << 3));
      acc[0][nf] = MFMA(a0, bb, acc[0][nf]);
      acc[1][nf] = MFMA(a1, bb, acc[1][nf]);
    }
  }

  // epilogue per wm-group: relu+b3 -> LDS -> vector store in dec A-frag layout
  for (int g = 0; g < 4; ++g) {
    __syncthreads();
    if (wm == g) {
      #pragma unroll
      for (int mf = 0; mf < 2; ++mf)
        #pragma unroll
        for (int nf = 0; nf < 8; ++nf) {
          int col = wn * 128 + nf * 16 + l15;
          float bias = b3[col];
          #pragma unroll
          for (int rr = 0; rr < 4; ++rr) {
            int rl = mf * 16 + lg * 4 + rr;
            sh[rl * 512 + col] = f2bf(fmaxf(acc[mf][nf][rr] + bias, 0.f));
          }
        }
    }
    __syncthreads();
    #pragma unroll
    for (int it = 0; it < 2; ++it) {
      int c = it * 1024 + tid;
      int tl = c >> 6, k0 = (c >> 2) & 15, gg = c & 3;
      int t = t0 + g * 32 + tl;
      long dst = ((long)(((b * 256 + t) * 16 + k0) * 64 + gg * 16 + a)) << 3;
      *(s16x8*)(h3p + dst) = *(const s16x8*)&sh[tl * 512 + k0 * 32 + gg * 8];
    }
  }
}

// ---------------- decoder: q = relu(h3@w4+b4)@w5+b5 ----------------
__global__ __launch_bounds__(512, 4) void dec_kernel(
    const short* __restrict__ h3p, const short* __restrict__ w4p,
    const float* __restrict__ b4, const short* __restrict__ w5p,
    const float* __restrict__ b5, float* __restrict__ out)
{
  __shared__ short h4s[16384] __attribute__((aligned(16)));  // 64 x 256 half
  const int tid = threadIdx.x;
  const int lane = tid & 63, wid = tid >> 6;
  const int wm = wid >> 2, wn = wid & 3;
  const int mf5 = wid >> 1, nf5 = wid & 1;
  const int l15 = lane & 15, lg = lane >> 4;
  const int rb = blockIdx.x << 6;

  f32x4 z = {0.f, 0.f, 0.f, 0.f};
  f32x4 acc5 = z;
  const short* aB0 = h3p + ((rb >> 4) + wm * 2) * 8192 + lane * 8;
  const short* aB1 = aB0 + 8192;

  for (int nh = 0; nh < 2; ++nh) {
    f32x4 acc[2][4];
    #pragma unroll
    for (int i = 0; i < 2; ++i)
      #pragma unroll
      for (int j = 0; j < 4; ++j) acc[i][j] = z;

    #pragma unroll 2
    for (int k0 = 0; k0 < 16; ++k0) {
      s16x8 a0 = *(const s16x8*)(aB0 + k0 * 512);
      s16x8 a1 = *(const s16x8*)(aB1 + k0 * 512);
      #pragma unroll
      for (int nf = 0; nf < 4; ++nf) {
        s16x8 bb = *(const s16x8*)(w4p + (((nh * 16 + wn * 4 + nf) * 16 + k0) * 64 + lane) * 8);
        acc[0][nf] = MFMA(a0, bb, acc[0][nf]);
        acc[1][nf] = MFMA(a1, bb, acc[1][nf]);
      }
    }
    if (nh == 1) __syncthreads();
    #pragma unroll
    for (int mf = 0; mf < 2; ++mf)
      #pragma unroll
      for (int nf = 0; nf < 4; ++nf) {
        int col = wn * 64 + nf * 16 + l15;
        float bias = b4[nh * 256 + col];
        #pragma unroll
        for (int rr = 0; rr < 4; ++rr) {
          int row = wm * 32 + mf * 16 + lg * 4 + rr;
          float v = fmaxf(acc[mf][nf][rr] + bias, 0.f);
          int by = ((row << 9) + (col << 1)) ^ ((row & 7) << 4);
          h4s[by >> 1] = f2bf(v);
        }
      }
    __syncthreads();
    #pragma unroll
    for (int kk = 0; kk < 8; ++kk) {
      int row0 = mf5 * 16 + l15;
      int by = ((row0 << 9) + (kk << 6) + (lg << 4)) ^ ((row0 & 7) << 4);
      s16x8 a0 = *(const s16x8*)((const char*)h4s + by);
      s16x8 bb = *(const s16x8*)(w5p + ((nf5 * 16 + nh * 8 + kk) * 64 + lane) * 8);
      acc5 = MFMA(a0, bb, acc5);
    }
  }
  int col = nf5 * 16 + l15;
  if (col < 30) {
    float bias = b5[col];
    #pragma unroll
    for (int rr = 0; rr < 4; ++rr) {
      int row = rb + mf5 * 16 + lg * 4 + rr;
      out[row * 30 + col] = acc5[rr] + bias;
    }
  }
}

// ---------------- carried window output (unswizzle seq frames 256..262) ----------------
__global__ __launch_bounds__(256) void win_out_kernel(
    const short* __restrict__ seqp, float* __restrict__ out)
{
  int idx = blockIdx.x * 256 + threadIdx.x;  // 458752
  int d  = idx & 127;
  int r  = idx >> 7;
  int i  = r % 7;
  int ba = r / 7;
  int f = 256 + i;                    // f&7 == i
  int s = (d >> 3) ^ i;
  out[3932160 + idx] = bf2f(seqp[(ba * SEQ_T + f) * 128 + s * 8 + (d & 7)]);
}

extern "C" void kernel_launch(void* const* d_in, const int* in_sizes, int n_in,
                              void* d_out, int out_size, void* d_ws, size_t ws_size,
                              hipStream_t stream) {
  const float* inp = (const float*)d_in[0];
  const float* hid = (const float*)d_in[1];
  const float* w1  = (const float*)d_in[2];
  const float* b1  = (const float*)d_in[3];
  const float* w2  = (const float*)d_in[4];
  const float* b2  = (const float*)d_in[5];
  const float* w3  = (const float*)d_in[6];
  const float* b3  = (const float*)d_in[7];
  const float* w4  = (const float*)d_in[8];
  const float* b4  = (const float*)d_in[9];
  const float* w5  = (const float*)d_in[10];
  const float* b5  = (const float*)d_in[11];

  char* ws = (char*)d_ws;
  short* wp   = (short*)ws;
  short* w1p  = wp;
  short* w2p  = wp + W2P_OFF;
  short* w3p  = wp + W3P_OFF;
  short* w4p  = wp + W4P_OFF;
  short* w5p  = wp + W5P_OFF;
  short* seqp = (short*)(ws + SEQ_BYTE_OFF);
  short* bigp = (short*)(ws + BIG_BYTE_OFF);  // Apack for enc, then aliased as h3p
  float* out  = (float*)d_out;

  pack_w_kernel  <<<WP_TOTAL / 256, 256, 0, stream>>>(w1, w2, w3, w4, w5, wp);
  pack_inp_kernel<<<32768, 256, 0, stream>>>(inp, bigp);
  hid_copy_kernel<<<1792, 256, 0, stream>>>(hid, seqp);
  enc_kernel     <<<2048, 512, 0, stream>>>(bigp, w1p, b1, w2p, b2, seqp);
  win_kernel     <<<1024, 1024, 0, stream>>>(seqp, w3p, b3, bigp);
  dec_kernel     <<<2048, 512, 0, stream>>>(bigp, w4p, b4, w5p, b5, out);
  win_out_kernel <<<1792, 256, 0, stream>>>(seqp, out);
}

// Round 2
// 921.898 us; speedup vs baseline: 1.1626x; 1.1626x over previous
//
#include <hip/hip_runtime.h>
#include <hip/hip_bf16.h>

// SlidingFFAgent: fused 5-layer MLP + sliding window, bf16 MFMA pipeline.
// Round 2: kill scratch spills in enc (4 n-quarter passes, acc1[2][4]) and
// win (2 n-half passes, acc[2][4] + separate repack LDS buffer).

#define DEVI __device__ __forceinline__

typedef float f32x4 __attribute__((ext_vector_type(4)));
typedef short s16x8 __attribute__((ext_vector_type(8)));

#define ROWS 131072
#define SEQ_T 263

// packed weight offsets (in shorts)
#define W2P_OFF 524288
#define W3P_OFF 655360
#define W4P_OFF 1179648
#define W5P_OFF 1441792
#define WP_TOTAL 1458176

#define SEQ_BYTE_OFF 2916352
#define BIG_BYTE_OFF 37388288   // Apack (enc input frags), later aliased as h3p

DEVI short f2bf(float f) {
  union { __hip_bfloat16 h; short s; } u;
  u.h = __float2bfloat16(f);
  return u.s;
}
DEVI float bf2f(short s) {
  union { __hip_bfloat16 h; short s; } u;
  u.s = s;
  return __bfloat162float(u.h);
}

DEVI f32x4 MFMA(s16x8 a, s16x8 b, f32x4 c) {
  return __builtin_amdgcn_mfma_f32_16x16x32_bf16(a, b, c, 0, 0, 0);
}

// ---------------- weight packing: W[k][n] f32 -> B-frag-packed bf16 ----------------
__global__ __launch_bounds__(256) void pack_w_kernel(
    const float* __restrict__ w1, const float* __restrict__ w2,
    const float* __restrict__ w3, const float* __restrict__ w4,
    const float* __restrict__ w5, short* __restrict__ wp)
{
  int idx = blockIdx.x * 256 + threadIdx.x;
  const float* src; int sh, Nsrc, local;
  if (idx < W2P_OFF)      { src = w1; sh = 4; Nsrc = 1024; local = idx; }
  else if (idx < W3P_OFF) { src = w2; sh = 5; Nsrc = 128;  local = idx - W2P_OFF; }
  else if (idx < W4P_OFF) { src = w3; sh = 5; Nsrc = 512;  local = idx - W3P_OFF; }
  else if (idx < W5P_OFF) { src = w4; sh = 4; Nsrc = 512;  local = idx - W4P_OFF; }
  else                    { src = w5; sh = 4; Nsrc = 30;   local = idx - W5P_OFF; }
  int j    = local & 7;
  int lane = (local >> 3) & 63;
  int rest = local >> 9;
  int k0   = rest & ((1 << sh) - 1);
  int n0   = rest >> sh;
  int k = (k0 << 5) + ((lane >> 4) << 3) + j;
  int n = (n0 << 4) + (lane & 15);
  float v = (n < Nsrc) ? src[k * Nsrc + n] : 0.f;
  wp[idx] = f2bf(v);
}

// ---------------- inputs f32 -> A-frag-packed bf16 ----------------
__global__ __launch_bounds__(256) void pack_inp_kernel(
    const float* __restrict__ inp, short* __restrict__ ap)
{
  int c = blockIdx.x * 256 + threadIdx.x;     // 16B chunk index, 8,388,608 total
  int l  = c & 63;
  int k0 = (c >> 6) & 15;
  int mt = c >> 10;
  int row = (mt << 4) | (l & 15);
  int kb  = (k0 << 5) | ((l >> 4) << 3);
  const float* s = inp + row * 512 + kb;
  f32x4 v0 = *(const f32x4*)s;
  f32x4 v1 = *(const f32x4*)(s + 4);
  s16x8 o;
  o[0]=f2bf(v0[0]); o[1]=f2bf(v0[1]); o[2]=f2bf(v0[2]); o[3]=f2bf(v0[3]);
  o[4]=f2bf(v1[0]); o[5]=f2bf(v1[1]); o[6]=f2bf(v1[2]); o[7]=f2bf(v1[3]);
  *(s16x8*)(ap + (long)c * 8) = o;
}

// ---------------- hidden_state -> seq frames 0..6 (pre-swizzled) ----------------
__global__ __launch_bounds__(256) void hid_copy_kernel(
    const float* __restrict__ hid, short* __restrict__ seqp)
{
  int idx = blockIdx.x * 256 + threadIdx.x;   // 458752 total
  int d  = idx & 127;
  int r  = idx >> 7;
  int i  = r % 7;
  int ba = r / 7;
  int s  = (d >> 3) ^ i;
  seqp[(ba * SEQ_T + i) * 128 + s * 8 + (d & 7)] = f2bf(hid[idx]);
}

// ---------------- encoder: x2 = relu(relu(inp@w1+b1)@w2+b2) -> seq ----------------
// 4 n-quarter passes: stage1 quarter (64x256, acc1[2][4]) -> LDS -> partial stage2.
__global__ __launch_bounds__(512, 4) void enc_kernel(
    const short* __restrict__ ap, const short* __restrict__ w1p,
    const float* __restrict__ b1, const short* __restrict__ w2p,
    const float* __restrict__ b2, short* __restrict__ seqp)
{
  __shared__ short h1s[16384] __attribute__((aligned(16)));  // 32KB: 64 x 256
  const int tid = threadIdx.x;
  const int lane = tid & 63, wid = tid >> 6;
  const int wm = wid >> 2, wn = wid & 3;
  const int l15 = lane & 15, lg = lane >> 4;
  const int rb = blockIdx.x << 6;

  f32x4 z = {0.f, 0.f, 0.f, 0.f};
  f32x4 acc2[2][2] = {{z, z}, {z, z}};
  const short* aB0 = ap + ((rb >> 4) + wm * 2) * 8192 + lane * 8;
  const short* aB1 = aB0 + 8192;

  for (int q = 0; q < 4; ++q) {
    f32x4 acc1[2][4];
    #pragma unroll
    for (int i = 0; i < 2; ++i)
      #pragma unroll
      for (int j = 0; j < 4; ++j) acc1[i][j] = z;

    // stage1 quarter: cols [q*256, q*256+256), manual A prefetch
    s16x8 a0 = *(const s16x8*)(aB0);
    s16x8 a1 = *(const s16x8*)(aB1);
    #pragma unroll 1
    for (int k0 = 0; k0 < 16; ++k0) {
      int kn = (k0 + 1) & 15;
      s16x8 na0 = *(const s16x8*)(aB0 + kn * 512);
      s16x8 na1 = *(const s16x8*)(aB1 + kn * 512);
      #pragma unroll
      for (int nf = 0; nf < 4; ++nf) {
        s16x8 bb = *(const s16x8*)(w1p + ((q * 16 + wn * 4 + nf) * 16 + k0) * 512 + lane * 8);
        acc1[0][nf] = MFMA(a0, bb, acc1[0][nf]);
        acc1[1][nf] = MFMA(a1, bb, acc1[1][nf]);
      }
      a0 = na0; a1 = na1;
    }
    __syncthreads();  // prev stage2 done reading h1s
    // write h1 quarter (relu+b1) into swizzled LDS (row stride 512B)
    #pragma unroll
    for (int mf = 0; mf < 2; ++mf)
      #pragma unroll
      for (int nf = 0; nf < 4; ++nf) {
        int lc = wn * 64 + nf * 16 + l15;
        float bias = b1[q * 256 + lc];
        #pragma unroll
        for (int rr = 0; rr < 4; ++rr) {
          int row = wm * 32 + mf * 16 + lg * 4 + rr;
          float v = fmaxf(acc1[mf][nf][rr] + bias, 0.f);
          int by = ((row << 9) + (lc << 1)) ^ ((row & 7) << 4);
          h1s[by >> 1] = f2bf(v);
        }
      }
    __syncthreads();
    // stage2 partial: x2 += h1q @ w2[kfrags q*8 .. q*8+8)
    #pragma unroll 2
    for (int kk = 0; kk < 8; ++kk) {
      int row0 = wm * 32 + l15;
      int row1 = row0 + 16;
      int by0 = ((row0 << 9) + (kk << 6) + (lg << 4)) ^ ((row0 & 7) << 4);
      int by1 = ((row1 << 9) + (kk << 6) + (lg << 4)) ^ ((row1 & 7) << 4);
      s16x8 s0 = *(const s16x8*)((const char*)h1s + by0);
      s16x8 s1 = *(const s16x8*)((const char*)h1s + by1);
      #pragma unroll
      for (int nf = 0; nf < 2; ++nf) {
        s16x8 bb = *(const s16x8*)(w2p + (((wn * 2 + nf) * 32 + q * 8 + kk) * 64 + lane) * 8);
        acc2[0][nf] = MFMA(s0, bb, acc2[0][nf]);
        acc2[1][nf] = MFMA(s1, bb, acc2[1][nf]);
      }
    }
  }
  // epilogue: repack x2 via LDS, vector store to pre-swizzled seq
  __syncthreads();
  #pragma unroll
  for (int mf = 0; mf < 2; ++mf)
    #pragma unroll
    for (int nf = 0; nf < 2; ++nf) {
      int col = wn * 32 + nf * 16 + l15;
      float bias = b2[col];
      #pragma unroll
      for (int rr = 0; rr < 4; ++rr) {
        int row = wm * 32 + mf * 16 + lg * 4 + rr;
        float v = fmaxf(acc2[mf][nf][rr] + bias, 0.f);
        h1s[row * 128 + col] = f2bf(v);
      }
    }
  __syncthreads();
  #pragma unroll
  for (int it = 0; it < 2; ++it) {
    int c = it * 512 + tid;
    int row = c >> 4, s = c & 15;
    int R = rb + row;
    int b = R >> 12, t = (R >> 4) & 255, a2 = R & 15;
    int f = t + 7;
    int dst = ((b * 16 + a2) * SEQ_T + f) * 128 + ((s ^ (f & 7)) * 8);
    *(s16x8*)(seqp + dst) = *(const s16x8*)&h1s[row * 128 + s * 8];
  }
}

// ---------------- sliding-window GEMM: h3 = relu(wins@w3+b3) -> frag-packed ----------------
// 2 n-half passes: acc[2][4]; seq stays in sh; epilogue via separate swizzled rp buffer.
__global__ __launch_bounds__(1024, 4) void win_kernel(
    const short* __restrict__ seqp, const short* __restrict__ w3p,
    const float* __restrict__ b3, short* __restrict__ h3p)
{
  __shared__ short sh[17280] __attribute__((aligned(16)));  // 135 frames staged (34.5KB)
  __shared__ short rp[32768] __attribute__((aligned(16)));  // 128 x 256 repack (64KB)
  const int tid = threadIdx.x;
  const int lane = tid & 63, wid = tid >> 6;
  const int wm = wid >> 2, wn = wid & 3;
  const int l15 = lane & 15, lg = lane >> 4;
  const int bid = blockIdx.x;
  const int th = bid & 1, ba = bid >> 1;
  const int b = ba >> 4, a = ba & 15;
  const int t0 = th << 7;

  // stage 135 frames (pre-swizzled global -> linear LDS copy keeps swizzle)
  const short* gsrc = seqp + (ba * SEQ_T + t0) * 128;
  #pragma unroll
  for (int i = 0; i < 3; ++i) {
    int c = i * 1024 + tid;
    if (c < 2160) *(s16x8*)&sh[c * 8] = *(const s16x8*)(gsrc + c * 8);
  }
  __syncthreads();

  f32x4 z = {0.f, 0.f, 0.f, 0.f};
  for (int h = 0; h < 2; ++h) {
    f32x4 acc[2][4];
    #pragma unroll
    for (int i = 0; i < 2; ++i)
      #pragma unroll
      for (int j = 0; j < 4; ++j) acc[i][j] = z;

    #pragma unroll 1
    for (int kc = 0; kc < 32; ++kc) {
      int w = kc >> 2;
      int dby = ((kc & 3) << 6) + (lg << 4);
      int f0 = wm * 32 + l15 + w;
      int f1 = f0 + 16;
      s16x8 a0 = *(const s16x8*)((const char*)sh + (((f0 << 8) + dby) ^ ((f0 & 7) << 4)));
      s16x8 a1 = *(const s16x8*)((const char*)sh + (((f1 << 8) + dby) ^ ((f1 & 7) << 4)));
      #pragma unroll
      for (int nf = 0; nf < 4; ++nf) {
        s16x8 bb = *(const s16x8*)(w3p + (((wn * 8 + h * 4 + nf) * 32 + kc) * 64 + lane) * 8);
        acc[0][nf] = MFMA(a0, bb, acc[0][nf]);
        acc[1][nf] = MFMA(a1, bb, acc[1][nf]);
      }
    }

    __syncthreads();  // main loop done (and prev half's copy done reading rp)
    // write relu'd half (cols with bit6==h) into swizzled rp: 128 rows x 256
    #pragma unroll
    for (int mf = 0; mf < 2; ++mf)
      #pragma unroll
      for (int nf = 0; nf < 4; ++nf) {
        int lc = wn * 64 + nf * 16 + l15;
        float bias = b3[wn * 128 + h * 64 + nf * 16 + l15];
        #pragma unroll
        for (int rr = 0; rr < 4; ++rr) {
          int rl = wm * 32 + mf * 16 + lg * 4 + rr;
          float v = fmaxf(acc[mf][nf][rr] + bias, 0.f);
          int by = ((rl << 9) + (lc << 1)) ^ ((rl & 7) << 4);
          rp[by >> 1] = f2bf(v);
        }
      }
    __syncthreads();
    // copy rp -> h3p (dec A-frag layout), 4096 chunks of 16B
    #pragma unroll
    for (int it = 0; it < 4; ++it) {
      int c = it * 1024 + tid;
      int tl = c >> 5;
      int khi = (c >> 3) & 3;
      int klo = (c >> 2) & 1;
      int gg  = c & 3;
      int k0 = khi * 4 + h * 2 + klo;
      int t = t0 + tl;
      int lc = khi * 64 + klo * 32 + gg * 8;
      int by = ((tl << 9) + (lc << 1)) ^ ((tl & 7) << 4);
      long dst = ((long)(((b * 256 + t) * 16 + k0) * 64 + gg * 16 + a)) << 3;
      *(s16x8*)(h3p + dst) = *(const s16x8*)((const char*)rp + by);
    }
  }
}

// ---------------- decoder: q = relu(h3@w4+b4)@w5+b5 ----------------
__global__ __launch_bounds__(512, 4) void dec_kernel(
    const short* __restrict__ h3p, const short* __restrict__ w4p,
    const float* __restrict__ b4, const short* __restrict__ w5p,
    const float* __restrict__ b5, float* __restrict__ out)
{
  __shared__ short h4s[16384] __attribute__((aligned(16)));  // 64 x 256 half
  const int tid = threadIdx.x;
  const int lane = tid & 63, wid = tid >> 6;
  const int wm = wid >> 2, wn = wid & 3;
  const int mf5 = wid >> 1, nf5 = wid & 1;
  const int l15 = lane & 15, lg = lane >> 4;
  const int rb = blockIdx.x << 6;

  f32x4 z = {0.f, 0.f, 0.f, 0.f};
  f32x4 acc5 = z;
  const short* aB0 = h3p + ((rb >> 4) + wm * 2) * 8192 + lane * 8;
  const short* aB1 = aB0 + 8192;

  for (int nh = 0; nh < 2; ++nh) {
    f32x4 acc[2][4];
    #pragma unroll
    for (int i = 0; i < 2; ++i)
      #pragma unroll
      for (int j = 0; j < 4; ++j) acc[i][j] = z;

    #pragma unroll 2
    for (int k0 = 0; k0 < 16; ++k0) {
      s16x8 a0 = *(const s16x8*)(aB0 + k0 * 512);
      s16x8 a1 = *(const s16x8*)(aB1 + k0 * 512);
      #pragma unroll
      for (int nf = 0; nf < 4; ++nf) {
        s16x8 bb = *(const s16x8*)(w4p + (((nh * 16 + wn * 4 + nf) * 16 + k0) * 64 + lane) * 8);
        acc[0][nf] = MFMA(a0, bb, acc[0][nf]);
        acc[1][nf] = MFMA(a1, bb, acc[1][nf]);
      }
    }
    if (nh == 1) __syncthreads();
    #pragma unroll
    for (int mf = 0; mf < 2; ++mf)
      #pragma unroll
      for (int nf = 0; nf < 4; ++nf) {
        int col = wn * 64 + nf * 16 + l15;
        float bias = b4[nh * 256 + col];
        #pragma unroll
        for (int rr = 0; rr < 4; ++rr) {
          int row = wm * 32 + mf * 16 + lg * 4 + rr;
          float v = fmaxf(acc[mf][nf][rr] + bias, 0.f);
          int by = ((row << 9) + (col << 1)) ^ ((row & 7) << 4);
          h4s[by >> 1] = f2bf(v);
        }
      }
    __syncthreads();
    #pragma unroll
    for (int kk = 0; kk < 8; ++kk) {
      int row0 = mf5 * 16 + l15;
      int by = ((row0 << 9) + (kk << 6) + (lg << 4)) ^ ((row0 & 7) << 4);
      s16x8 a0 = *(const s16x8*)((const char*)h4s + by);
      s16x8 bb = *(const s16x8*)(w5p + ((nf5 * 16 + nh * 8 + kk) * 64 + lane) * 8);
      acc5 = MFMA(a0, bb, acc5);
    }
  }
  int col = nf5 * 16 + l15;
  if (col < 30) {
    float bias = b5[col];
    #pragma unroll
    for (int rr = 0; rr < 4; ++rr) {
      int row = rb + mf5 * 16 + lg * 4 + rr;
      out[row * 30 + col] = acc5[rr] + bias;
    }
  }
}

// ---------------- carried window output (unswizzle seq frames 256..262) ----------------
__global__ __launch_bounds__(256) void win_out_kernel(
    const short* __restrict__ seqp, float* __restrict__ out)
{
  int idx = blockIdx.x * 256 + threadIdx.x;  // 458752
  int d  = idx & 127;
  int r  = idx >> 7;
  int i  = r % 7;
  int ba = r / 7;
  int f = 256 + i;
  int s = (d >> 3) ^ i;
  out[3932160 + idx] = bf2f(seqp[(ba * SEQ_T + f) * 128 + s * 8 + (d & 7)]);
}

extern "C" void kernel_launch(void* const* d_in, const int* in_sizes, int n_in,
                              void* d_out, int out_size, void* d_ws, size_t ws_size,
                              hipStream_t stream) {
  const float* inp = (const float*)d_in[0];
  const float* hid = (const float*)d_in[1];
  const float* w1  = (const float*)d_in[2];
  const float* b1  = (const float*)d_in[3];
  const float* w2  = (const float*)d_in[4];
  const float* b2  = (const float*)d_in[5];
  const float* w3  = (const float*)d_in[6];
  const float* b3  = (const float*)d_in[7];
  const float* w4  = (const float*)d_in[8];
  const float* b4  = (const float*)d_in[9];
  const float* w5  = (const float*)d_in[10];
  const float* b5  = (const float*)d_in[11];

  char* ws = (char*)d_ws;
  short* wp   = (short*)ws;
  short* w1p  = wp;
  short* w2p  = wp + W2P_OFF;
  short* w3p  = wp + W3P_OFF;
  short* w4p  = wp + W4P_OFF;
  short* w5p  = wp + W5P_OFF;
  short* seqp = (short*)(ws + SEQ_BYTE_OFF);
  short* bigp = (short*)(ws + BIG_BYTE_OFF);
  float* out  = (float*)d_out;

  pack_w_kernel  <<<WP_TOTAL / 256, 256, 0, stream>>>(w1, w2, w3, w4, w5, wp);
  pack_inp_kernel<<<32768, 256, 0, stream>>>(inp, bigp);
  hid_copy_kernel<<<1792, 256, 0, stream>>>(hid, seqp);
  enc_kernel     <<<2048, 512, 0, stream>>>(bigp, w1p, b1, w2p, b2, seqp);
  win_kernel     <<<1024, 1024, 0, stream>>>(seqp, w3p, b3, bigp);
  dec_kernel     <<<2048, 512, 0, stream>>>(bigp, w4p, b4, w5p, b5, out);
  win_out_kernel <<<1792, 256, 0, stream>>>(seqp, out);
}

// Round 3
// 863.003 us; speedup vs baseline: 1.2419x; 1.0682x over previous
//
#include <hip/hip_runtime.h>
#include <hip/hip_bf16.h>

// SlidingFFAgent: fused 5-layer MLP + sliding window, bf16 MFMA pipeline.
// Round 3: dec M-tiles re-enumerated as (b,a,t/16) so win writes h3p coalesced;
// acc[4][4] waves with explicit B-prefetch; 2 blocks/CU on enc/win/dec.

#define DEVI __device__ __forceinline__

typedef float f32x4 __attribute__((ext_vector_type(4)));
typedef short s16x8 __attribute__((ext_vector_type(8)));

#define ROWS 131072
#define SEQ_T 263

// packed weight offsets (in shorts)
#define W2P_OFF 524288
#define W3P_OFF 655360
#define W4P_OFF 1179648
#define W5P_OFF 1441792
#define WP_TOTAL 1458176

#define SEQ_BYTE_OFF 2916352
#define BIG_BYTE_OFF 37388288   // Apack (enc input frags), later aliased as h3p

DEVI short f2bf(float f) {
  union { __hip_bfloat16 h; short s; } u;
  u.h = __float2bfloat16(f);
  return u.s;
}
DEVI float bf2f(short s) {
  union { __hip_bfloat16 h; short s; } u;
  u.s = s;
  return __bfloat162float(u.h);
}

DEVI f32x4 MFMA(s16x8 a, s16x8 b, f32x4 c) {
  return __builtin_amdgcn_mfma_f32_16x16x32_bf16(a, b, c, 0, 0, 0);
}

// ---------------- weight packing: W[k][n] f32 -> B-frag-packed bf16 ----------------
__global__ __launch_bounds__(256) void pack_w_kernel(
    const float* __restrict__ w1, const float* __restrict__ w2,
    const float* __restrict__ w3, const float* __restrict__ w4,
    const float* __restrict__ w5, short* __restrict__ wp)
{
  int idx = blockIdx.x * 256 + threadIdx.x;
  const float* src; int sh, Nsrc, local;
  if (idx < W2P_OFF)      { src = w1; sh = 4; Nsrc = 1024; local = idx; }
  else if (idx < W3P_OFF) { src = w2; sh = 5; Nsrc = 128;  local = idx - W2P_OFF; }
  else if (idx < W4P_OFF) { src = w3; sh = 5; Nsrc = 512;  local = idx - W3P_OFF; }
  else if (idx < W5P_OFF) { src = w4; sh = 4; Nsrc = 512;  local = idx - W4P_OFF; }
  else                    { src = w5; sh = 4; Nsrc = 30;   local = idx - W5P_OFF; }
  int j    = local & 7;
  int lane = (local >> 3) & 63;
  int rest = local >> 9;
  int k0   = rest & ((1 << sh) - 1);
  int n0   = rest >> sh;
  int k = (k0 << 5) + ((lane >> 4) << 3) + j;
  int n = (n0 << 4) + (lane & 15);
  float v = (n < Nsrc) ? src[k * Nsrc + n] : 0.f;
  wp[idx] = f2bf(v);
}

// ---------------- inputs f32 -> A-frag-packed bf16 ----------------
__global__ __launch_bounds__(256) void pack_inp_kernel(
    const float* __restrict__ inp, short* __restrict__ ap)
{
  int c = blockIdx.x * 256 + threadIdx.x;     // 16B chunk index, 8,388,608 total
  int l  = c & 63;
  int k0 = (c >> 6) & 15;
  int mt = c >> 10;
  int row = (mt << 4) | (l & 15);
  int kb  = (k0 << 5) | ((l >> 4) << 3);
  const float* s = inp + row * 512 + kb;
  f32x4 v0 = *(const f32x4*)s;
  f32x4 v1 = *(const f32x4*)(s + 4);
  s16x8 o;
  o[0]=f2bf(v0[0]); o[1]=f2bf(v0[1]); o[2]=f2bf(v0[2]); o[3]=f2bf(v0[3]);
  o[4]=f2bf(v1[0]); o[5]=f2bf(v1[1]); o[6]=f2bf(v1[2]); o[7]=f2bf(v1[3]);
  *(s16x8*)(ap + (long)c * 8) = o;
}

// ---------------- hidden_state -> seq frames 0..6 (pre-swizzled) ----------------
__global__ __launch_bounds__(256) void hid_copy_kernel(
    const float* __restrict__ hid, short* __restrict__ seqp)
{
  int idx = blockIdx.x * 256 + threadIdx.x;   // 458752 total
  int d  = idx & 127;
  int r  = idx >> 7;
  int i  = r % 7;
  int ba = r / 7;
  int s  = (d >> 3) ^ i;
  seqp[(ba * SEQ_T + i) * 128 + s * 8 + (d & 7)] = f2bf(hid[idx]);
}

// ---------------- encoder: x2 = relu(relu(inp@w1+b1)@w2+b2) -> seq ----------------
// 128-row blocks, 8 waves (wm 0..1 x wn 0..3); 8 n-passes of 128 cols.
__global__ __launch_bounds__(512, 4) void enc_kernel(
    const short* __restrict__ ap, const short* __restrict__ w1p,
    const float* __restrict__ b1, const short* __restrict__ w2p,
    const float* __restrict__ b2, short* __restrict__ seqp)
{
  __shared__ short h1s[16384] __attribute__((aligned(16)));  // 128 x 128, swizzled
  const int tid = threadIdx.x;
  const int lane = tid & 63, wid = tid >> 6;
  const int wm = wid >> 2, wn = wid & 3;
  const int l15 = lane & 15, lg = lane >> 4;
  const int rb = blockIdx.x << 7;

  f32x4 z = {0.f, 0.f, 0.f, 0.f};
  f32x4 acc2[4][2] = {{z, z}, {z, z}, {z, z}, {z, z}};
  const short* aBase = ap + ((rb >> 4) + wm * 4) * 8192 + lane * 8;

  for (int q = 0; q < 8; ++q) {
    f32x4 acc1[4][2] = {{z, z}, {z, z}, {z, z}, {z, z}};
    const short* bB = w1p + ((q * 8 + wn * 2) * 16) * 512 + lane * 8;

    s16x8 av[4], bb[2];
    #pragma unroll
    for (int mf = 0; mf < 4; ++mf) av[mf] = *(const s16x8*)(aBase + mf * 8192);
    #pragma unroll
    for (int nf = 0; nf < 2; ++nf) bb[nf] = *(const s16x8*)(bB + (nf * 16) * 512);

    #pragma unroll 1
    for (int k0 = 0; k0 < 16; ++k0) {
      int kn = (k0 + 1) & 15;
      s16x8 avn[4], bbn[2];
      #pragma unroll
      for (int mf = 0; mf < 4; ++mf) avn[mf] = *(const s16x8*)(aBase + mf * 8192 + kn * 512);
      #pragma unroll
      for (int nf = 0; nf < 2; ++nf) bbn[nf] = *(const s16x8*)(bB + (nf * 16 + kn) * 512);
      #pragma unroll
      for (int nf = 0; nf < 2; ++nf)
        #pragma unroll
        for (int mf = 0; mf < 4; ++mf)
          acc1[mf][nf] = MFMA(av[mf], bb[nf], acc1[mf][nf]);
      #pragma unroll
      for (int mf = 0; mf < 4; ++mf) av[mf] = avn[mf];
      #pragma unroll
      for (int nf = 0; nf < 2; ++nf) bb[nf] = bbn[nf];
    }
    __syncthreads();  // prev stage2 done reading h1s
    // write h1 pass (relu+b1) into swizzled LDS (128 x 128, row stride 256B)
    #pragma unroll
    for (int mf = 0; mf < 4; ++mf)
      #pragma unroll
      for (int nf = 0; nf < 2; ++nf) {
        int lc = wn * 32 + nf * 16 + l15;
        float bias = b1[q * 128 + lc];
        #pragma unroll
        for (int rr = 0; rr < 4; ++rr) {
          int row = wm * 64 + mf * 16 + lg * 4 + rr;
          float v = fmaxf(acc1[mf][nf][rr] + bias, 0.f);
          int by = ((row << 8) + (lc << 1)) ^ ((row & 7) << 4);
          h1s[by >> 1] = f2bf(v);
        }
      }
    __syncthreads();
    // stage2 partial: x2 += h1pass @ w2[kfrags q*4 .. q*4+4)
    #pragma unroll
    for (int kk = 0; kk < 4; ++kk) {
      int kf = q * 4 + kk;
      s16x8 sa[4];
      #pragma unroll
      for (int mf = 0; mf < 4; ++mf) {
        int row = wm * 64 + mf * 16 + l15;
        int by = ((row << 8) + (kk << 6) + (lg << 4)) ^ ((row & 7) << 4);
        sa[mf] = *(const s16x8*)((const char*)h1s + by);
      }
      #pragma unroll
      for (int nf = 0; nf < 2; ++nf) {
        s16x8 wb = *(const s16x8*)(w2p + ((wn * 2 + nf) * 32 + kf) * 512 + lane * 8);
        #pragma unroll
        for (int mf = 0; mf < 4; ++mf)
          acc2[mf][nf] = MFMA(sa[mf], wb, acc2[mf][nf]);
      }
    }
  }
  // epilogue: x2 relu+b2 -> h1s (swizzled) -> coalesced store to pre-swizzled seq
  __syncthreads();
  #pragma unroll
  for (int mf = 0; mf < 4; ++mf)
    #pragma unroll
    for (int nf = 0; nf < 2; ++nf) {
      int lc = wn * 32 + nf * 16 + l15;
      float bias = b2[lc];
      #pragma unroll
      for (int rr = 0; rr < 4; ++rr) {
        int row = wm * 64 + mf * 16 + lg * 4 + rr;
        float v = fmaxf(acc2[mf][nf][rr] + bias, 0.f);
        int by = ((row << 8) + (lc << 1)) ^ ((row & 7) << 4);
        h1s[by >> 1] = f2bf(v);
      }
    }
  __syncthreads();
  #pragma unroll
  for (int it = 0; it < 4; ++it) {
    int c = it * 512 + tid;
    int s = c & 15, i = c >> 4;
    int by = ((i << 8) + (s << 4)) ^ ((i & 7) << 4);
    int r = rb + i;
    int ba2 = ((r >> 12) << 4) + (r & 15);
    int t = (r >> 4) & 255;
    int f = t + 7;
    int dst = (ba2 * SEQ_T + f) * 128 + ((s ^ (f & 7)) * 8);
    *(s16x8*)(seqp + dst) = *(const s16x8*)((const char*)h1s + by);
  }
}

// ---------------- sliding-window GEMM: h3 = relu(wins@w3+b3) -> dec A-frags ----------------
// block = (ba, th): 128 t's for one (b,a). 8 waves; 2 n-half passes, acc[4][4].
__global__ __launch_bounds__(512, 4) void win_kernel(
    const short* __restrict__ seqp, const short* __restrict__ w3p,
    const float* __restrict__ b3, short* __restrict__ h3p)
{
  __shared__ short sh[17280] __attribute__((aligned(16)));  // 135 frames (34.5KB)
  __shared__ short rp[16384] __attribute__((aligned(16)));  // 128 x 128 repack (32KB)
  const int tid = threadIdx.x;
  const int lane = tid & 63, wid = tid >> 6;
  const int wm = wid >> 2, wn = wid & 3;   // wm 0..1, wn 0..3
  const int l15 = lane & 15, lg = lane >> 4;
  const int bid = blockIdx.x;
  const int th = bid & 1, ba = bid >> 1;
  const int t0 = th << 7;

  // stage 135 frames (pre-swizzled global -> linear LDS copy keeps swizzle)
  const short* gsrc = seqp + (ba * SEQ_T + t0) * 128;
  #pragma unroll
  for (int i = 0; i < 5; ++i) {
    int c = i * 512 + tid;
    if (c < 2160) *(s16x8*)&sh[c * 8] = *(const s16x8*)(gsrc + c * 8);
  }
  __syncthreads();

  f32x4 z = {0.f, 0.f, 0.f, 0.f};
  for (int h = 0; h < 2; ++h) {
    f32x4 acc[4][4];
    #pragma unroll
    for (int i = 0; i < 4; ++i)
      #pragma unroll
      for (int j = 0; j < 4; ++j) acc[i][j] = z;

    const short* bB = w3p + ((h * 16 + wn * 4) * 32) * 512 + lane * 8;
    s16x8 bcur[4];
    #pragma unroll
    for (int nf = 0; nf < 4; ++nf) bcur[nf] = *(const s16x8*)(bB + (nf * 32) * 512);

    #pragma unroll 1
    for (int kc = 0; kc < 32; ++kc) {
      int kn = (kc + 1) & 31;
      s16x8 bnxt[4];
      #pragma unroll
      for (int nf = 0; nf < 4; ++nf) bnxt[nf] = *(const s16x8*)(bB + (nf * 32 + kn) * 512);
      int w = kc >> 2;
      int dby = ((kc & 3) << 6) + (lg << 4);
      s16x8 av[4];
      #pragma unroll
      for (int mf = 0; mf < 4; ++mf) {
        int f = wm * 64 + mf * 16 + l15 + w;
        av[mf] = *(const s16x8*)((const char*)sh + (((f << 8) + dby) ^ ((f & 7) << 4)));
      }
      #pragma unroll
      for (int nf = 0; nf < 4; ++nf)
        #pragma unroll
        for (int mf = 0; mf < 4; ++mf)
          acc[mf][nf] = MFMA(av[mf], bcur[nf], acc[mf][nf]);
      #pragma unroll
      for (int nf = 0; nf < 4; ++nf) bcur[nf] = bnxt[nf];
    }

    // epilogue: 2 sub-passes of 128 cols (nf pairs {2s,2s+1})
    for (int s = 0; s < 2; ++s) {
      __syncthreads();
      #pragma unroll
      for (int mf = 0; mf < 4; ++mf)
        #pragma unroll
        for (int e = 0; e < 2; ++e) {
          int nf = s * 2 + e;
          float bias = b3[h * 256 + wn * 64 + nf * 16 + l15];
          int lc = wn * 32 + e * 16 + l15;
          #pragma unroll
          for (int rr = 0; rr < 4; ++rr) {
            int row = wm * 64 + mf * 16 + lg * 4 + rr;
            float v = fmaxf(acc[mf][nf][rr] + bias, 0.f);
            int by = ((row << 8) + (lc << 1)) ^ ((row & 7) << 4);
            rp[by >> 1] = f2bf(v);
          }
        }
      __syncthreads();
      // copy rp -> h3p, coalesced 1KB runs
      #pragma unroll
      for (int it = 0; it < 4; ++it) {
        int c = it * 512 + tid;
        int cl = c & 15, g = (c >> 4) & 3, kq = (c >> 6) & 3, tt = (c >> 8) & 7;
        int row = tt * 16 + cl;
        int by = ((row << 8) + (kq << 6) + (g << 4)) ^ ((row & 7) << 4);
        int k0g = h * 8 + kq * 2 + s;
        int mt = ba * 16 + th * 8 + tt;
        long dst = ((long)((mt * 16 + k0g) * 64 + g * 16 + cl)) << 3;
        *(s16x8*)(h3p + dst) = *(const s16x8*)((const char*)rp + by);
      }
    }
  }
}

// ---------------- decoder: q = relu(h3@w4+b4)@w5+b5 ----------------
// 128-row blocks (M-tiles = (b,a,t/16)); 8 waves; 2 n-half passes, acc[4][4].
__global__ __launch_bounds__(512, 4) void dec_kernel(
    const short* __restrict__ h3p, const short* __restrict__ w4p,
    const float* __restrict__ b4, const short* __restrict__ w5p,
    const float* __restrict__ b5, float* __restrict__ out)
{
  __shared__ short h4s[32768] __attribute__((aligned(16)));  // 128 x 256 half, swizzled
  const int tid = threadIdx.x;
  const int lane = tid & 63, wid = tid >> 6;
  const int wm = wid >> 2, wn = wid & 3;
  const int mf5 = wid;  // 0..7 for w5 stage
  const int l15 = lane & 15, lg = lane >> 4;
  const int rb = blockIdx.x << 7;

  f32x4 z = {0.f, 0.f, 0.f, 0.f};
  f32x4 acc5[2] = {z, z};
  const short* aBase = h3p + ((rb >> 4) + wm * 4) * 8192 + lane * 8;

  for (int h = 0; h < 2; ++h) {
    f32x4 acc[4][4];
    #pragma unroll
    for (int i = 0; i < 4; ++i)
      #pragma unroll
      for (int j = 0; j < 4; ++j) acc[i][j] = z;

    const short* bB = w4p + ((h * 16 + wn * 4) * 16) * 512 + lane * 8;
    s16x8 bcur[4];
    #pragma unroll
    for (int nf = 0; nf < 4; ++nf) bcur[nf] = *(const s16x8*)(bB + (nf * 16) * 512);

    #pragma unroll 1
    for (int k0 = 0; k0 < 16; ++k0) {
      int kn = (k0 + 1) & 15;
      s16x8 bnxt[4];
      #pragma unroll
      for (int nf = 0; nf < 4; ++nf) bnxt[nf] = *(const s16x8*)(bB + (nf * 16 + kn) * 512);
      s16x8 av[4];
      #pragma unroll
      for (int mf = 0; mf < 4; ++mf) av[mf] = *(const s16x8*)(aBase + mf * 8192 + k0 * 512);
      #pragma unroll
      for (int nf = 0; nf < 4; ++nf)
        #pragma unroll
        for (int mf = 0; mf < 4; ++mf)
          acc[mf][nf] = MFMA(av[mf], bcur[nf], acc[mf][nf]);
      #pragma unroll
      for (int nf = 0; nf < 4; ++nf) bcur[nf] = bnxt[nf];
    }
    __syncthreads();  // prev w5 stage done reading h4s
    #pragma unroll
    for (int mf = 0; mf < 4; ++mf)
      #pragma unroll
      for (int nf = 0; nf < 4; ++nf) {
        int lc = wn * 64 + nf * 16 + l15;
        float bias = b4[h * 256 + lc];
        #pragma unroll
        for (int rr = 0; rr < 4; ++rr) {
          int row = wm * 64 + mf * 16 + lg * 4 + rr;
          float v = fmaxf(acc[mf][nf][rr] + bias, 0.f);
          int by = ((row << 9) + (lc << 1)) ^ ((row & 7) << 4);
          h4s[by >> 1] = f2bf(v);
        }
      }
    __syncthreads();
    #pragma unroll
    for (int kk = 0; kk < 8; ++kk) {
      int row = mf5 * 16 + l15;
      int by = ((row << 9) + (kk << 6) + (lg << 4)) ^ ((row & 7) << 4);
      s16x8 a0 = *(const s16x8*)((const char*)h4s + by);
      #pragma unroll
      for (int nf = 0; nf < 2; ++nf) {
        s16x8 wb = *(const s16x8*)(w5p + (nf * 16 + h * 8 + kk) * 512 + lane * 8);
        acc5[nf] = MFMA(a0, wb, acc5[nf]);
      }
    }
  }
  #pragma unroll
  for (int nf = 0; nf < 2; ++nf) {
    int col = nf * 16 + l15;
    if (col < 30) {
      float bias = b5[col];
      #pragma unroll
      for (int rr = 0; rr < 4; ++rr) {
        int row_ = rb + mf5 * 16 + lg * 4 + rr;
        int t = row_ & 255;
        int ba2 = row_ >> 8;
        int orow = (((ba2 >> 4) << 8) + t) * 16 + (ba2 & 15);
        out[orow * 30 + col] = acc5[nf][rr] + bias;
      }
    }
  }
}

// ---------------- carried window output (unswizzle seq frames 256..262) ----------------
__global__ __launch_bounds__(256) void win_out_kernel(
    const short* __restrict__ seqp, float* __restrict__ out)
{
  int idx = blockIdx.x * 256 + threadIdx.x;  // 458752
  int d  = idx & 127;
  int r  = idx >> 7;
  int i  = r % 7;
  int ba = r / 7;
  int f = 256 + i;
  int s = (d >> 3) ^ i;
  out[3932160 + idx] = bf2f(seqp[(ba * SEQ_T + f) * 128 + s * 8 + (d & 7)]);
}

extern "C" void kernel_launch(void* const* d_in, const int* in_sizes, int n_in,
                              void* d_out, int out_size, void* d_ws, size_t ws_size,
                              hipStream_t stream) {
  const float* inp = (const float*)d_in[0];
  const float* hid = (const float*)d_in[1];
  const float* w1  = (const float*)d_in[2];
  const float* b1  = (const float*)d_in[3];
  const float* w2  = (const float*)d_in[4];
  const float* b2  = (const float*)d_in[5];
  const float* w3  = (const float*)d_in[6];
  const float* b3  = (const float*)d_in[7];
  const float* w4  = (const float*)d_in[8];
  const float* b4  = (const float*)d_in[9];
  const float* w5  = (const float*)d_in[10];
  const float* b5  = (const float*)d_in[11];

  char* ws = (char*)d_ws;
  short* wp   = (short*)ws;
  short* w1p  = wp;
  short* w2p  = wp + W2P_OFF;
  short* w3p  = wp + W3P_OFF;
  short* w4p  = wp + W4P_OFF;
  short* w5p  = wp + W5P_OFF;
  short* seqp = (short*)(ws + SEQ_BYTE_OFF);
  short* bigp = (short*)(ws + BIG_BYTE_OFF);
  float* out  = (float*)d_out;

  pack_w_kernel  <<<WP_TOTAL / 256, 256, 0, stream>>>(w1, w2, w3, w4, w5, wp);
  pack_inp_kernel<<<32768, 256, 0, stream>>>(inp, bigp);
  hid_copy_kernel<<<1792, 256, 0, stream>>>(hid, seqp);
  enc_kernel     <<<1024, 512, 0, stream>>>(bigp, w1p, b1, w2p, b2, seqp);
  win_kernel     <<<1024, 512, 0, stream>>>(seqp, w3p, b3, bigp);
  dec_kernel     <<<1024, 512, 0, stream>>>(bigp, w4p, b4, w5p, b5, out);
  win_out_kernel <<<1792, 256, 0, stream>>>(seqp, out);
}

// Round 4
// 681.033 us; speedup vs baseline: 1.5737x; 1.2672x over previous
//
#include <hip/hip_runtime.h>
#include <hip/hip_bf16.h>

// SlidingFFAgent: fused 5-layer MLP + sliding window, bf16 MFMA pipeline.
// Round 4: enc rewritten — raw f32 input staged once into swizzled LDS A-tile
// (A read from HBM exactly once); pack_inp kernel eliminated.

#define DEVI __device__ __forceinline__

typedef float f32x4 __attribute__((ext_vector_type(4)));
typedef short s16x8 __attribute__((ext_vector_type(8)));

#define ROWS 131072
#define SEQ_T 263

// packed weight offsets (in shorts)
#define W2P_OFF 524288
#define W3P_OFF 655360
#define W4P_OFF 1179648
#define W5P_OFF 1441792
#define WP_TOTAL 1458176

#define SEQ_BYTE_OFF 2916352
#define BIG_BYTE_OFF 37388288   // h3p (win output -> dec input)

DEVI short f2bf(float f) {
  union { __hip_bfloat16 h; short s; } u;
  u.h = __float2bfloat16(f);
  return u.s;
}
DEVI float bf2f(short s) {
  union { __hip_bfloat16 h; short s; } u;
  u.s = s;
  return __bfloat162float(u.h);
}

DEVI f32x4 MFMA(s16x8 a, s16x8 b, f32x4 c) {
  return __builtin_amdgcn_mfma_f32_16x16x32_bf16(a, b, c, 0, 0, 0);
}

// ---------------- weight packing: W[k][n] f32 -> B-frag-packed bf16 ----------------
__global__ __launch_bounds__(256) void pack_w_kernel(
    const float* __restrict__ w1, const float* __restrict__ w2,
    const float* __restrict__ w3, const float* __restrict__ w4,
    const float* __restrict__ w5, short* __restrict__ wp)
{
  int idx = blockIdx.x * 256 + threadIdx.x;
  const float* src; int sh, Nsrc, local;
  if (idx < W2P_OFF)      { src = w1; sh = 4; Nsrc = 1024; local = idx; }
  else if (idx < W3P_OFF) { src = w2; sh = 5; Nsrc = 128;  local = idx - W2P_OFF; }
  else if (idx < W4P_OFF) { src = w3; sh = 5; Nsrc = 512;  local = idx - W3P_OFF; }
  else if (idx < W5P_OFF) { src = w4; sh = 4; Nsrc = 512;  local = idx - W4P_OFF; }
  else                    { src = w5; sh = 4; Nsrc = 30;   local = idx - W5P_OFF; }
  int j    = local & 7;
  int lane = (local >> 3) & 63;
  int rest = local >> 9;
  int k0   = rest & ((1 << sh) - 1);
  int n0   = rest >> sh;
  int k = (k0 << 5) + ((lane >> 4) << 3) + j;
  int n = (n0 << 4) + (lane & 15);
  float v = (n < Nsrc) ? src[k * Nsrc + n] : 0.f;
  wp[idx] = f2bf(v);
}

// ---------------- hidden_state -> seq frames 0..6 (pre-swizzled) ----------------
__global__ __launch_bounds__(256) void hid_copy_kernel(
    const float* __restrict__ hid, short* __restrict__ seqp)
{
  int idx = blockIdx.x * 256 + threadIdx.x;   // 458752 total
  int d  = idx & 127;
  int r  = idx >> 7;
  int i  = r % 7;
  int ba = r / 7;
  int s  = (d >> 3) ^ i;
  seqp[(ba * SEQ_T + i) * 128 + s * 8 + (d & 7)] = f2bf(hid[idx]);
}

// ---------------- encoder: x2 = relu(relu(inp@w1+b1)@w2+b2) -> seq ----------------
// M=64 blocks; A staged once (f32->bf16) into swizzled LDS; 8 n-passes of 128 cols.
// 8 waves = wm(0..3, m-frag) x wn(0..1, n-half-of-pass).
__global__ __launch_bounds__(512, 4) void enc_kernel(
    const float* __restrict__ inp, const short* __restrict__ w1p,
    const float* __restrict__ b1, const short* __restrict__ w2p,
    const float* __restrict__ b2, short* __restrict__ seqp)
{
  __shared__ short As[32768] __attribute__((aligned(16)));   // 64x512 bf16, swizzled (64KB)
  __shared__ short h1q[8192] __attribute__((aligned(16)));   // 64x128 bf16, swizzled (16KB)
  const int tid = threadIdx.x;
  const int lane = tid & 63, wid = tid >> 6;
  const int wm = wid >> 1, wn = wid & 1;
  const int l15 = lane & 15, lg = lane >> 4;
  const int rb = blockIdx.x << 6;

  // ---- stage A: raw f32 rows -> bf16 swizzled LDS (read HBM once) ----
  #pragma unroll
  for (int it = 0; it < 8; ++it) {
    int g = it * 512 + tid;            // 4096 x 16B chunks
    int row = g >> 6, j = g & 63;      // wave reads one full 2KB row, coalesced
    const float* s = inp + (long)(rb + row) * 512 + j * 8;
    f32x4 v0 = *(const f32x4*)s;
    f32x4 v1 = *(const f32x4*)(s + 4);
    s16x8 o;
    o[0]=f2bf(v0[0]); o[1]=f2bf(v0[1]); o[2]=f2bf(v0[2]); o[3]=f2bf(v0[3]);
    o[4]=f2bf(v1[0]); o[5]=f2bf(v1[1]); o[6]=f2bf(v1[2]); o[7]=f2bf(v1[3]);
    int by = ((row << 10) + (j << 4)) ^ ((row & 7) << 4);
    *(s16x8*)((char*)As + by) = o;
  }
  __syncthreads();

  f32x4 z = {0.f, 0.f, 0.f, 0.f};
  f32x4 acc2[4] = {z, z, z, z};
  const int arow = wm * 16 + l15;
  const int asw = (arow & 7) << 4;
  const int abase = (arow << 10) + (lg << 4);

  for (int q = 0; q < 8; ++q) {
    f32x4 acc1[4] = {z, z, z, z};
    const short* bB = w1p + ((q * 8 + wn * 4) * 16) * 512 + lane * 8;

    s16x8 acur = *(const s16x8*)((const char*)As + (abase ^ asw));
    s16x8 bcur[4];
    #pragma unroll
    for (int nf = 0; nf < 4; ++nf) bcur[nf] = *(const s16x8*)(bB + (nf * 16) * 512);

    #pragma unroll 1
    for (int k0 = 0; k0 < 16; ++k0) {
      int kn = (k0 + 1) & 15;
      s16x8 anxt = *(const s16x8*)((const char*)As + ((abase + (kn << 6)) ^ asw));
      s16x8 bnxt[4];
      #pragma unroll
      for (int nf = 0; nf < 4; ++nf) bnxt[nf] = *(const s16x8*)(bB + (nf * 16 + kn) * 512);
      #pragma unroll
      for (int nf = 0; nf < 4; ++nf)
        acc1[nf] = MFMA(acur, bcur[nf], acc1[nf]);
      acur = anxt;
      #pragma unroll
      for (int nf = 0; nf < 4; ++nf) bcur[nf] = bnxt[nf];
    }
    __syncthreads();  // prev stage2 done reading h1q
    // write h1 pass (relu+b1) into swizzled h1q (64 x 128, row stride 256B)
    #pragma unroll
    for (int nf = 0; nf < 4; ++nf) {
      int lc = wn * 64 + nf * 16 + l15;
      float bias = b1[q * 128 + lc];
      #pragma unroll
      for (int rr = 0; rr < 4; ++rr) {
        int row = wm * 16 + lg * 4 + rr;
        float v = fmaxf(acc1[nf][rr] + bias, 0.f);
        int by = ((row << 8) + (lc << 1)) ^ ((row & 7) << 4);
        h1q[by >> 1] = f2bf(v);
      }
    }
    __syncthreads();
    // stage2 partial: x2 += h1q @ w2[kfrags q*4 .. q*4+4)
    #pragma unroll
    for (int kk = 0; kk < 4; ++kk) {
      int kf = q * 4 + kk;
      int by = ((arow << 8) + (kk << 6) + (lg << 4)) ^ ((arow & 7) << 4);
      s16x8 sa = *(const s16x8*)((const char*)h1q + by);
      #pragma unroll
      for (int nf = 0; nf < 4; ++nf) {
        s16x8 wb = *(const s16x8*)(w2p + (((wn * 4 + nf) * 32 + kf) * 64 + lane) * 8);
        acc2[nf] = MFMA(sa, wb, acc2[nf]);
      }
    }
  }
  // epilogue: x2 relu+b2 -> h1q (swizzled) -> coalesced store to pre-swizzled seq
  __syncthreads();
  #pragma unroll
  for (int nf = 0; nf < 4; ++nf) {
    int lc = wn * 64 + nf * 16 + l15;
    float bias = b2[lc];
    #pragma unroll
    for (int rr = 0; rr < 4; ++rr) {
      int row = wm * 16 + lg * 4 + rr;
      float v = fmaxf(acc2[nf][rr] + bias, 0.f);
      int by = ((row << 8) + (lc << 1)) ^ ((row & 7) << 4);
      h1q[by >> 1] = f2bf(v);
    }
  }
  __syncthreads();
  #pragma unroll
  for (int it = 0; it < 2; ++it) {
    int c = it * 512 + tid;
    int s = c & 15, i = c >> 4;
    int by = ((i << 8) + (s << 4)) ^ ((i & 7) << 4);
    int r = rb + i;
    int ba2 = ((r >> 12) << 4) + (r & 15);
    int t = (r >> 4) & 255;
    int f = t + 7;
    int dst = (ba2 * SEQ_T + f) * 128 + ((s ^ (f & 7)) * 8);
    *(s16x8*)(seqp + dst) = *(const s16x8*)((const char*)h1q + by);
  }
}

// ---------------- sliding-window GEMM: h3 = relu(wins@w3+b3) -> dec A-frags ----------------
// block = (ba, th): 128 t's for one (b,a). 8 waves; 2 n-half passes, acc[4][4].
__global__ __launch_bounds__(512, 4) void win_kernel(
    const short* __restrict__ seqp, const short* __restrict__ w3p,
    const float* __restrict__ b3, short* __restrict__ h3p)
{
  __shared__ short sh[17280] __attribute__((aligned(16)));  // 135 frames (34.5KB)
  __shared__ short rp[16384] __attribute__((aligned(16)));  // 128 x 128 repack (32KB)
  const int tid = threadIdx.x;
  const int lane = tid & 63, wid = tid >> 6;
  const int wm = wid >> 2, wn = wid & 3;   // wm 0..1, wn 0..3
  const int l15 = lane & 15, lg = lane >> 4;
  const int bid = blockIdx.x;
  const int th = bid & 1, ba = bid >> 1;
  const int t0 = th << 7;

  // stage 135 frames (pre-swizzled global -> linear LDS copy keeps swizzle)
  const short* gsrc = seqp + (ba * SEQ_T + t0) * 128;
  #pragma unroll
  for (int i = 0; i < 5; ++i) {
    int c = i * 512 + tid;
    if (c < 2160) *(s16x8*)&sh[c * 8] = *(const s16x8*)(gsrc + c * 8);
  }
  __syncthreads();

  f32x4 z = {0.f, 0.f, 0.f, 0.f};
  for (int h = 0; h < 2; ++h) {
    f32x4 acc[4][4];
    #pragma unroll
    for (int i = 0; i < 4; ++i)
      #pragma unroll
      for (int j = 0; j < 4; ++j) acc[i][j] = z;

    const short* bB = w3p + ((h * 16 + wn * 4) * 32) * 512 + lane * 8;
    s16x8 bcur[4];
    #pragma unroll
    for (int nf = 0; nf < 4; ++nf) bcur[nf] = *(const s16x8*)(bB + (nf * 32) * 512);

    #pragma unroll 1
    for (int kc = 0; kc < 32; ++kc) {
      int kn = (kc + 1) & 31;
      s16x8 bnxt[4];
      #pragma unroll
      for (int nf = 0; nf < 4; ++nf) bnxt[nf] = *(const s16x8*)(bB + (nf * 32 + kn) * 512);
      int w = kc >> 2;
      int dby = ((kc & 3) << 6) + (lg << 4);
      s16x8 av[4];
      #pragma unroll
      for (int mf = 0; mf < 4; ++mf) {
        int f = wm * 64 + mf * 16 + l15 + w;
        av[mf] = *(const s16x8*)((const char*)sh + (((f << 8) + dby) ^ ((f & 7) << 4)));
      }
      #pragma unroll
      for (int nf = 0; nf < 4; ++nf)
        #pragma unroll
        for (int mf = 0; mf < 4; ++mf)
          acc[mf][nf] = MFMA(av[mf], bcur[nf], acc[mf][nf]);
      #pragma unroll
      for (int nf = 0; nf < 4; ++nf) bcur[nf] = bnxt[nf];
    }

    // epilogue: 2 sub-passes of 128 cols (nf pairs {2s,2s+1})
    for (int s = 0; s < 2; ++s) {
      __syncthreads();
      #pragma unroll
      for (int mf = 0; mf < 4; ++mf)
        #pragma unroll
        for (int e = 0; e < 2; ++e) {
          int nf = s * 2 + e;
          float bias = b3[h * 256 + wn * 64 + nf * 16 + l15];
          int lc = wn * 32 + e * 16 + l15;
          #pragma unroll
          for (int rr = 0; rr < 4; ++rr) {
            int row = wm * 64 + mf * 16 + lg * 4 + rr;
            float v = fmaxf(acc[mf][nf][rr] + bias, 0.f);
            int by = ((row << 8) + (lc << 1)) ^ ((row & 7) << 4);
            rp[by >> 1] = f2bf(v);
          }
        }
      __syncthreads();
      // copy rp -> h3p, coalesced 1KB runs
      #pragma unroll
      for (int it = 0; it < 4; ++it) {
        int c = it * 512 + tid;
        int cl = c & 15, g = (c >> 4) & 3, kq = (c >> 6) & 3, tt = (c >> 8) & 7;
        int row = tt * 16 + cl;
        int by = ((row << 8) + (kq << 6) + (g << 4)) ^ ((row & 7) << 4);
        int k0g = h * 8 + kq * 2 + s;
        int mt = ba * 16 + th * 8 + tt;
        long dst = ((long)((mt * 16 + k0g) * 64 + g * 16 + cl)) << 3;
        *(s16x8*)(h3p + dst) = *(const s16x8*)((const char*)rp + by);
      }
    }
  }
}

// ---------------- decoder: q = relu(h3@w4+b4)@w5+b5 ----------------
// 128-row blocks (M-tiles = (b,a,t/16)); 8 waves; 2 n-half passes, acc[4][4].
__global__ __launch_bounds__(512, 4) void dec_kernel(
    const short* __restrict__ h3p, const short* __restrict__ w4p,
    const float* __restrict__ b4, const short* __restrict__ w5p,
    const float* __restrict__ b5, float* __restrict__ out)
{
  __shared__ short h4s[32768] __attribute__((aligned(16)));  // 128 x 256 half, swizzled
  const int tid = threadIdx.x;
  const int lane = tid & 63, wid = tid >> 6;
  const int wm = wid >> 2, wn = wid & 3;
  const int mf5 = wid;  // 0..7 for w5 stage
  const int l15 = lane & 15, lg = lane >> 4;
  const int rb = blockIdx.x << 7;

  f32x4 z = {0.f, 0.f, 0.f, 0.f};
  f32x4 acc5[2] = {z, z};
  const short* aBase = h3p + ((rb >> 4) + wm * 4) * 8192 + lane * 8;

  for (int h = 0; h < 2; ++h) {
    f32x4 acc[4][4];
    #pragma unroll
    for (int i = 0; i < 4; ++i)
      #pragma unroll
      for (int j = 0; j < 4; ++j) acc[i][j] = z;

    const short* bB = w4p + ((h * 16 + wn * 4) * 16) * 512 + lane * 8;
    s16x8 bcur[4];
    #pragma unroll
    for (int nf = 0; nf < 4; ++nf) bcur[nf] = *(const s16x8*)(bB + (nf * 16) * 512);

    #pragma unroll 1
    for (int k0 = 0; k0 < 16; ++k0) {
      int kn = (k0 + 1) & 15;
      s16x8 bnxt[4];
      #pragma unroll
      for (int nf = 0; nf < 4; ++nf) bnxt[nf] = *(const s16x8*)(bB + (nf * 16 + kn) * 512);
      s16x8 av[4];
      #pragma unroll
      for (int mf = 0; mf < 4; ++mf) av[mf] = *(const s16x8*)(aBase + mf * 8192 + k0 * 512);
      #pragma unroll
      for (int nf = 0; nf < 4; ++nf)
        #pragma unroll
        for (int mf = 0; mf < 4; ++mf)
          acc[mf][nf] = MFMA(av[mf], bcur[nf], acc[mf][nf]);
      #pragma unroll
      for (int nf = 0; nf < 4; ++nf) bcur[nf] = bnxt[nf];
    }
    __syncthreads();  // prev w5 stage done reading h4s
    #pragma unroll
    for (int mf = 0; mf < 4; ++mf)
      #pragma unroll
      for (int nf = 0; nf < 4; ++nf) {
        int lc = wn * 64 + nf * 16 + l15;
        float bias = b4[h * 256 + lc];
        #pragma unroll
        for (int rr = 0; rr < 4; ++rr) {
          int row = wm * 64 + mf * 16 + lg * 4 + rr;
          float v = fmaxf(acc[mf][nf][rr] + bias, 0.f);
          int by = ((row << 9) + (lc << 1)) ^ ((row & 7) << 4);
          h4s[by >> 1] = f2bf(v);
        }
      }
    __syncthreads();
    #pragma unroll
    for (int kk = 0; kk < 8; ++kk) {
      int row = mf5 * 16 + l15;
      int by = ((row << 9) + (kk << 6) + (lg << 4)) ^ ((row & 7) << 4);
      s16x8 a0 = *(const s16x8*)((const char*)h4s + by);
      #pragma unroll
      for (int nf = 0; nf < 2; ++nf) {
        s16x8 wb = *(const s16x8*)(w5p + (nf * 16 + h * 8 + kk) * 512 + lane * 8);
        acc5[nf] = MFMA(a0, wb, acc5[nf]);
      }
    }
  }
  #pragma unroll
  for (int nf = 0; nf < 2; ++nf) {
    int col = nf * 16 + l15;
    if (col < 30) {
      float bias = b5[col];
      #pragma unroll
      for (int rr = 0; rr < 4; ++rr) {
        int row_ = rb + mf5 * 16 + lg * 4 + rr;
        int t = row_ & 255;
        int ba2 = row_ >> 8;
        int orow = (((ba2 >> 4) << 8) + t) * 16 + (ba2 & 15);
        out[orow * 30 + col] = acc5[nf][rr] + bias;
      }
    }
  }
}

// ---------------- carried window output (unswizzle seq frames 256..262) ----------------
__global__ __launch_bounds__(256) void win_out_kernel(
    const short* __restrict__ seqp, float* __restrict__ out)
{
  int idx = blockIdx.x * 256 + threadIdx.x;  // 458752
  int d  = idx & 127;
  int r  = idx >> 7;
  int i  = r % 7;
  int ba = r / 7;
  int f = 256 + i;
  int s = (d >> 3) ^ i;
  out[3932160 + idx] = bf2f(seqp[(ba * SEQ_T + f) * 128 + s * 8 + (d & 7)]);
}

extern "C" void kernel_launch(void* const* d_in, const int* in_sizes, int n_in,
                              void* d_out, int out_size, void* d_ws, size_t ws_size,
                              hipStream_t stream) {
  const float* inp = (const float*)d_in[0];
  const float* hid = (const float*)d_in[1];
  const float* w1  = (const float*)d_in[2];
  const float* b1  = (const float*)d_in[3];
  const float* w2  = (const float*)d_in[4];
  const float* b2  = (const float*)d_in[5];
  const float* w3  = (const float*)d_in[6];
  const float* b3  = (const float*)d_in[7];
  const float* w4  = (const float*)d_in[8];
  const float* b4  = (const float*)d_in[9];
  const float* w5  = (const float*)d_in[10];
  const float* b5  = (const float*)d_in[11];

  char* ws = (char*)d_ws;
  short* wp   = (short*)ws;
  short* w1p  = wp;
  short* w2p  = wp + W2P_OFF;
  short* w3p  = wp + W3P_OFF;
  short* w4p  = wp + W4P_OFF;
  short* w5p  = wp + W5P_OFF;
  short* seqp = (short*)(ws + SEQ_BYTE_OFF);
  short* h3p  = (short*)(ws + BIG_BYTE_OFF);
  float* out  = (float*)d_out;

  pack_w_kernel  <<<WP_TOTAL / 256, 256, 0, stream>>>(w1, w2, w3, w4, w5, wp);
  hid_copy_kernel<<<1792, 256, 0, stream>>>(hid, seqp);
  enc_kernel     <<<2048, 512, 0, stream>>>(inp, w1p, b1, w2p, b2, seqp);
  win_kernel     <<<1024, 512, 0, stream>>>(seqp, w3p, b3, h3p);
  dec_kernel     <<<1024, 512, 0, stream>>>(h3p, w4p, b4, w5p, b5, out);
  win_out_kernel <<<1792, 256, 0, stream>>>(seqp, out);
}

// Round 5
// 577.118 us; speedup vs baseline: 1.8571x; 1.1801x over previous
//
#include <hip/hip_runtime.h>
#include <hip/hip_bf16.h>

// SlidingFFAgent: fused 5-layer MLP + sliding window, bf16 MFMA pipeline.
// Round 5: enc rebuilt with swapped-operand MFMA (D = h1^T), waves partition N
// (no W-dup, 16 MFMA per 4 L2-loads + 4 LDS-reads), b64 vectorized handoffs.

#define DEVI __device__ __forceinline__

typedef float f32x4 __attribute__((ext_vector_type(4)));
typedef short s16x8 __attribute__((ext_vector_type(8)));
typedef short s16x4 __attribute__((ext_vector_type(4)));

#define ROWS 131072
#define SEQ_T 263

// packed weight offsets (in shorts)
#define W2P_OFF 524288
#define W3P_OFF 655360
#define W4P_OFF 1179648
#define W5P_OFF 1441792
#define WP_TOTAL 1458176

#define SEQ_BYTE_OFF 2916352
#define BIG_BYTE_OFF 37388288   // h3p (win output -> dec input)

DEVI short f2bf(float f) {
  union { __hip_bfloat16 h; short s; } u;
  u.h = __float2bfloat16(f);
  return u.s;
}
DEVI float bf2f(short s) {
  union { __hip_bfloat16 h; short s; } u;
  u.s = s;
  return __bfloat162float(u.h);
}

DEVI f32x4 MFMA(s16x8 a, s16x8 b, f32x4 c) {
  return __builtin_amdgcn_mfma_f32_16x16x32_bf16(a, b, c, 0, 0, 0);
}

// ---------------- weight packing: W[k][n] f32 -> frag-packed bf16 ----------------
// elem index: ((n0*K32 + k0)*64 + lane)*8 + j ; lane = ((k>>3)&3)<<4 | (n&15)
__global__ __launch_bounds__(256) void pack_w_kernel(
    const float* __restrict__ w1, const float* __restrict__ w2,
    const float* __restrict__ w3, const float* __restrict__ w4,
    const float* __restrict__ w5, short* __restrict__ wp)
{
  int idx = blockIdx.x * 256 + threadIdx.x;
  const float* src; int sh, Nsrc, local;
  if (idx < W2P_OFF)      { src = w1; sh = 4; Nsrc = 1024; local = idx; }
  else if (idx < W3P_OFF) { src = w2; sh = 5; Nsrc = 128;  local = idx - W2P_OFF; }
  else if (idx < W4P_OFF) { src = w3; sh = 5; Nsrc = 512;  local = idx - W3P_OFF; }
  else if (idx < W5P_OFF) { src = w4; sh = 4; Nsrc = 512;  local = idx - W4P_OFF; }
  else                    { src = w5; sh = 4; Nsrc = 30;   local = idx - W5P_OFF; }
  int j    = local & 7;
  int lane = (local >> 3) & 63;
  int rest = local >> 9;
  int k0   = rest & ((1 << sh) - 1);
  int n0   = rest >> sh;
  int k = (k0 << 5) + ((lane >> 4) << 3) + j;
  int n = (n0 << 4) + (lane & 15);
  float v = (n < Nsrc) ? src[k * Nsrc + n] : 0.f;
  wp[idx] = f2bf(v);
}

// ---------------- hidden_state -> seq frames 0..6 (pre-swizzled) ----------------
__global__ __launch_bounds__(256) void hid_copy_kernel(
    const float* __restrict__ hid, short* __restrict__ seqp)
{
  int idx = blockIdx.x * 256 + threadIdx.x;   // 458752 total
  int d  = idx & 127;
  int r  = idx >> 7;
  int i  = r % 7;
  int ba = r / 7;
  int s  = (d >> 3) ^ i;
  seqp[(ba * SEQ_T + i) * 128 + s * 8 + (d & 7)] = f2bf(hid[idx]);
}

// ---------------- encoder: x2 = relu(relu(inp@w1+b1)@w2+b2) -> seq ----------------
// M=64 rows/block; A staged once into swizzled LDS. 2 passes x 512 h1-cols.
// 8 waves partition N (64 cols each, 4 n-frags); every wave covers all 4 m-frags.
// Swapped MFMA: acc = mfma(Wfrag, Xfrag) => D[n][m] = h1^T  (row=n, col=m).
__global__ __launch_bounds__(512, 2) void enc_kernel(
    const float* __restrict__ inp, const short* __restrict__ w1p,
    const float* __restrict__ b1, const short* __restrict__ w2p,
    const float* __restrict__ b2, short* __restrict__ seqp)
{
  __shared__ short As[32768] __attribute__((aligned(16)));   // 64x512 bf16, swizzled (64KB)
  __shared__ short h1q[32768] __attribute__((aligned(16)));  // 64x512 bf16, swizzled (64KB)
  const int tid = threadIdx.x;
  const int lane = tid & 63, wv = tid >> 6;     // wave 0..7
  const int l15 = lane & 15, lg = lane >> 4;
  const int rb = blockIdx.x << 6;

  // ---- stage A: raw f32 rows -> bf16 swizzled LDS (read HBM once) ----
  #pragma unroll
  for (int it = 0; it < 8; ++it) {
    int g = it * 512 + tid;            // 4096 x 16B chunks
    int row = g >> 6, j = g & 63;
    const float* s = inp + (long)(rb + row) * 512 + j * 8;
    f32x4 v0 = *(const f32x4*)s;
    f32x4 v1 = *(const f32x4*)(s + 4);
    s16x8 o;
    o[0]=f2bf(v0[0]); o[1]=f2bf(v0[1]); o[2]=f2bf(v0[2]); o[3]=f2bf(v0[3]);
    o[4]=f2bf(v1[0]); o[5]=f2bf(v1[1]); o[6]=f2bf(v1[2]); o[7]=f2bf(v1[3]);
    int by = ((row << 10) + (j << 4)) ^ ((row & 7) << 4);
    *(s16x8*)((char*)As + by) = o;
  }
  __syncthreads();

  f32x4 z = {0.f, 0.f, 0.f, 0.f};
  f32x4 acc2[4] = {z, z, z, z};

  for (int p = 0; p < 2; ++p) {
    // ---- stage 1: h1^T[pass-cols, 64 rows], wave's cols = wv*64..+64 ----
    f32x4 acc1[4][4];   // [ci (n-frag)][mi (m-frag)]
    #pragma unroll
    for (int i = 0; i < 4; ++i)
      #pragma unroll
      for (int j = 0; j < 4; ++j) acc1[i][j] = z;

    const short* wB = w1p + (((p * 32 + wv * 4) * 16) << 9) + lane * 8;

    s16x8 Wc[4], Xc[4];
    #pragma unroll
    for (int ci = 0; ci < 4; ++ci) Wc[ci] = *(const s16x8*)(wB + ((ci * 16) << 9));
    #pragma unroll
    for (int mi = 0; mi < 4; ++mi) {
      int m = mi * 16 + l15;
      Xc[mi] = *(const s16x8*)((const char*)As + (((m << 10) + (lg << 4)) ^ ((m & 7) << 4)));
    }

    #pragma unroll 1
    for (int k0 = 0; k0 < 16; ++k0) {
      int kn = (k0 + 1) & 15;
      s16x8 Wn[4], Xn[4];
      #pragma unroll
      for (int ci = 0; ci < 4; ++ci) Wn[ci] = *(const s16x8*)(wB + ((ci * 16 + kn) << 9));
      #pragma unroll
      for (int mi = 0; mi < 4; ++mi) {
        int m = mi * 16 + l15;
        Xn[mi] = *(const s16x8*)((const char*)As + (((m << 10) + (kn << 6) + (lg << 4)) ^ ((m & 7) << 4)));
      }
      #pragma unroll
      for (int ci = 0; ci < 4; ++ci)
        #pragma unroll
        for (int mi = 0; mi < 4; ++mi)
          acc1[ci][mi] = MFMA(Wc[ci], Xc[mi], acc1[ci][mi]);
      #pragma unroll
      for (int ci = 0; ci < 4; ++ci) Wc[ci] = Wn[ci];
      #pragma unroll
      for (int mi = 0; mi < 4; ++mi) Xc[mi] = Xn[mi];
    }
    __syncthreads();  // prev pass's stage2 done reading h1q
    // ---- write h1^T (relu+b1) into h1q[m][k_local], b64 per frag ----
    #pragma unroll
    for (int ci = 0; ci < 4; ++ci) {
      f32x4 bv = *(const f32x4*)(b1 + p * 512 + wv * 64 + ci * 16 + lg * 4);
      #pragma unroll
      for (int mi = 0; mi < 4; ++mi) {
        int m = mi * 16 + l15;
        s16x4 o;
        #pragma unroll
        for (int j = 0; j < 4; ++j)
          o[j] = f2bf(fmaxf(acc1[ci][mi][j] + bv[j], 0.f));
        int by = ((m << 10) + (wv << 7) + (ci << 5) + (lg << 3)) ^ ((m & 7) << 4);
        *(s16x4*)((char*)h1q + by) = o;
      }
    }
    __syncthreads();
    // ---- stage 2: acc2 += mfma(w2frag, h1frag) over this pass's 512 k ----
    const short* w2B = w2p + (((wv * 32 + p * 16) << 9)) + lane * 8;
    s16x8 W2c = *(const s16x8*)(w2B);
    s16x8 X2c[4];
    #pragma unroll
    for (int mi = 0; mi < 4; ++mi) {
      int m = mi * 16 + l15;
      X2c[mi] = *(const s16x8*)((const char*)h1q + (((m << 10) + (lg << 4)) ^ ((m & 7) << 4)));
    }
    #pragma unroll 1
    for (int kk = 0; kk < 16; ++kk) {
      int kn = (kk + 1) & 15;
      s16x8 W2n = *(const s16x8*)(w2B + (kn << 9));
      s16x8 X2n[4];
      #pragma unroll
      for (int mi = 0; mi < 4; ++mi) {
        int m = mi * 16 + l15;
        X2n[mi] = *(const s16x8*)((const char*)h1q + (((m << 10) + (kn << 6) + (lg << 4)) ^ ((m & 7) << 4)));
      }
      #pragma unroll
      for (int mi = 0; mi < 4; ++mi)
        acc2[mi] = MFMA(W2c, X2c[mi], acc2[mi]);
      W2c = W2n;
      #pragma unroll
      for (int mi = 0; mi < 4; ++mi) X2c[mi] = X2n[mi];
    }
  }
  // ---- epilogue: x2^T frags (relu+b2) -> LDS (b64) -> coalesced seq stores ----
  __syncthreads();   // all stage2 reads of h1q finished
  {
    f32x4 bv = *(const f32x4*)(b2 + wv * 16 + lg * 4);
    #pragma unroll
    for (int mi = 0; mi < 4; ++mi) {
      int m = mi * 16 + l15;
      s16x4 o;
      #pragma unroll
      for (int j = 0; j < 4; ++j)
        o[j] = f2bf(fmaxf(acc2[mi][j] + bv[j], 0.f));
      int by = ((m << 8) + (wv << 5) + (lg << 3)) ^ ((m & 7) << 4);
      *(s16x4*)((char*)h1q + by) = o;
    }
  }
  __syncthreads();
  #pragma unroll
  for (int it = 0; it < 2; ++it) {
    int c = it * 512 + tid;
    int s = c & 15, i = c >> 4;
    int by = ((i << 8) + (s << 4)) ^ ((i & 7) << 4);
    int r = rb + i;
    int ba2 = ((r >> 12) << 4) + (r & 15);
    int t = (r >> 4) & 255;
    int f = t + 7;
    int dst = (ba2 * SEQ_T + f) * 128 + ((s ^ (f & 7)) * 8);
    *(s16x8*)(seqp + dst) = *(const s16x8*)((const char*)h1q + by);
  }
}

// ---------------- sliding-window GEMM: h3 = relu(wins@w3+b3) -> dec A-frags ----------------
// block = (ba, th): 128 t's for one (b,a). 8 waves; 2 n-half passes, acc[4][4].
__global__ __launch_bounds__(512, 4) void win_kernel(
    const short* __restrict__ seqp, const short* __restrict__ w3p,
    const float* __restrict__ b3, short* __restrict__ h3p)
{
  __shared__ short sh[17280] __attribute__((aligned(16)));  // 135 frames (34.5KB)
  __shared__ short rp[16384] __attribute__((aligned(16)));  // 128 x 128 repack (32KB)
  const int tid = threadIdx.x;
  const int lane = tid & 63, wid = tid >> 6;
  const int wm = wid >> 2, wn = wid & 3;   // wm 0..1, wn 0..3
  const int l15 = lane & 15, lg = lane >> 4;
  const int bid = blockIdx.x;
  const int th = bid & 1, ba = bid >> 1;
  const int t0 = th << 7;

  // stage 135 frames (pre-swizzled global -> linear LDS copy keeps swizzle)
  const short* gsrc = seqp + (ba * SEQ_T + t0) * 128;
  #pragma unroll
  for (int i = 0; i < 5; ++i) {
    int c = i * 512 + tid;
    if (c < 2160) *(s16x8*)&sh[c * 8] = *(const s16x8*)(gsrc + c * 8);
  }
  __syncthreads();

  f32x4 z = {0.f, 0.f, 0.f, 0.f};
  for (int h = 0; h < 2; ++h) {
    f32x4 acc[4][4];
    #pragma unroll
    for (int i = 0; i < 4; ++i)
      #pragma unroll
      for (int j = 0; j < 4; ++j) acc[i][j] = z;

    const short* bB = w3p + ((h * 16 + wn * 4) * 32) * 512 + lane * 8;
    s16x8 bcur[4];
    #pragma unroll
    for (int nf = 0; nf < 4; ++nf) bcur[nf] = *(const s16x8*)(bB + (nf * 32) * 512);

    #pragma unroll 1
    for (int kc = 0; kc < 32; ++kc) {
      int kn = (kc + 1) & 31;
      s16x8 bnxt[4];
      #pragma unroll
      for (int nf = 0; nf < 4; ++nf) bnxt[nf] = *(const s16x8*)(bB + (nf * 32 + kn) * 512);
      int w = kc >> 2;
      int dby = ((kc & 3) << 6) + (lg << 4);
      s16x8 av[4];
      #pragma unroll
      for (int mf = 0; mf < 4; ++mf) {
        int f = wm * 64 + mf * 16 + l15 + w;
        av[mf] = *(const s16x8*)((const char*)sh + (((f << 8) + dby) ^ ((f & 7) << 4)));
      }
      #pragma unroll
      for (int nf = 0; nf < 4; ++nf)
        #pragma unroll
        for (int mf = 0; mf < 4; ++mf)
          acc[mf][nf] = MFMA(av[mf], bcur[nf], acc[mf][nf]);
      #pragma unroll
      for (int nf = 0; nf < 4; ++nf) bcur[nf] = bnxt[nf];
    }

    // epilogue: 2 sub-passes of 128 cols (nf pairs {2s,2s+1})
    for (int s = 0; s < 2; ++s) {
      __syncthreads();
      #pragma unroll
      for (int mf = 0; mf < 4; ++mf)
        #pragma unroll
        for (int e = 0; e < 2; ++e) {
          int nf = s * 2 + e;
          float bias = b3[h * 256 + wn * 64 + nf * 16 + l15];
          int lc = wn * 32 + e * 16 + l15;
          #pragma unroll
          for (int rr = 0; rr < 4; ++rr) {
            int row = wm * 64 + mf * 16 + lg * 4 + rr;
            float v = fmaxf(acc[mf][nf][rr] + bias, 0.f);
            int by = ((row << 8) + (lc << 1)) ^ ((row & 7) << 4);
            rp[by >> 1] = f2bf(v);
          }
        }
      __syncthreads();
      // copy rp -> h3p, coalesced 1KB runs
      #pragma unroll
      for (int it = 0; it < 4; ++it) {
        int c = it * 512 + tid;
        int cl = c & 15, g = (c >> 4) & 3, kq = (c >> 6) & 3, tt = (c >> 8) & 7;
        int row = tt * 16 + cl;
        int by = ((row << 8) + (kq << 6) + (g << 4)) ^ ((row & 7) << 4);
        int k0g = h * 8 + kq * 2 + s;
        int mt = ba * 16 + th * 8 + tt;
        long dst = ((long)((mt * 16 + k0g) * 64 + g * 16 + cl)) << 3;
        *(s16x8*)(h3p + dst) = *(const s16x8*)((const char*)rp + by);
      }
    }
  }
}

// ---------------- decoder: q = relu(h3@w4+b4)@w5+b5 ----------------
// 128-row blocks (M-tiles = (b,a,t/16)); 8 waves; 2 n-half passes, acc[4][4].
__global__ __launch_bounds__(512, 4) void dec_kernel(
    const short* __restrict__ h3p, const short* __restrict__ w4p,
    const float* __restrict__ b4, const short* __restrict__ w5p,
    const float* __restrict__ b5, float* __restrict__ out)
{
  __shared__ short h4s[32768] __attribute__((aligned(16)));  // 128 x 256 half, swizzled
  const int tid = threadIdx.x;
  const int lane = tid & 63, wid = tid >> 6;
  const int wm = wid >> 2, wn = wid & 3;
  const int mf5 = wid;  // 0..7 for w5 stage
  const int l15 = lane & 15, lg = lane >> 4;
  const int rb = blockIdx.x << 7;

  f32x4 z = {0.f, 0.f, 0.f, 0.f};
  f32x4 acc5[2] = {z, z};
  const short* aBase = h3p + ((rb >> 4) + wm * 4) * 8192 + lane * 8;

  for (int h = 0; h < 2; ++h) {
    f32x4 acc[4][4];
    #pragma unroll
    for (int i = 0; i < 4; ++i)
      #pragma unroll
      for (int j = 0; j < 4; ++j) acc[i][j] = z;

    const short* bB = w4p + ((h * 16 + wn * 4) * 16) * 512 + lane * 8;
    s16x8 bcur[4];
    #pragma unroll
    for (int nf = 0; nf < 4; ++nf) bcur[nf] = *(const s16x8*)(bB + (nf * 16) * 512);

    #pragma unroll 1
    for (int k0 = 0; k0 < 16; ++k0) {
      int kn = (k0 + 1) & 15;
      s16x8 bnxt[4];
      #pragma unroll
      for (int nf = 0; nf < 4; ++nf) bnxt[nf] = *(const s16x8*)(bB + (nf * 16 + kn) * 512);
      s16x8 av[4];
      #pragma unroll
      for (int mf = 0; mf < 4; ++mf) av[mf] = *(const s16x8*)(aBase + mf * 8192 + k0 * 512);
      #pragma unroll
      for (int nf = 0; nf < 4; ++nf)
        #pragma unroll
        for (int mf = 0; mf < 4; ++mf)
          acc[mf][nf] = MFMA(av[mf], bcur[nf], acc[mf][nf]);
      #pragma unroll
      for (int nf = 0; nf < 4; ++nf) bcur[nf] = bnxt[nf];
    }
    __syncthreads();  // prev w5 stage done reading h4s
    #pragma unroll
    for (int mf = 0; mf < 4; ++mf)
      #pragma unroll
      for (int nf = 0; nf < 4; ++nf) {
        int lc = wn * 64 + nf * 16 + l15;
        float bias = b4[h * 256 + lc];
        #pragma unroll
        for (int rr = 0; rr < 4; ++rr) {
          int row = wm * 64 + mf * 16 + lg * 4 + rr;
          float v = fmaxf(acc[mf][nf][rr] + bias, 0.f);
          int by = ((row << 9) + (lc << 1)) ^ ((row & 7) << 4);
          h4s[by >> 1] = f2bf(v);
        }
      }
    __syncthreads();
    #pragma unroll
    for (int kk = 0; kk < 8; ++kk) {
      int row = mf5 * 16 + l15;
      int by = ((row << 9) + (kk << 6) + (lg << 4)) ^ ((row & 7) << 4);
      s16x8 a0 = *(const s16x8*)((const char*)h4s + by);
      #pragma unroll
      for (int nf = 0; nf < 2; ++nf) {
        s16x8 wb = *(const s16x8*)(w5p + (nf * 16 + h * 8 + kk) * 512 + lane * 8);
        acc5[nf] = MFMA(a0, wb, acc5[nf]);
      }
    }
  }
  #pragma unroll
  for (int nf = 0; nf < 2; ++nf) {
    int col = nf * 16 + l15;
    if (col < 30) {
      float bias = b5[col];
      #pragma unroll
      for (int rr = 0; rr < 4; ++rr) {
        int row_ = rb + mf5 * 16 + lg * 4 + rr;
        int t = row_ & 255;
        int ba2 = row_ >> 8;
        int orow = (((ba2 >> 4) << 8) + t) * 16 + (ba2 & 15);
        out[orow * 30 + col] = acc5[nf][rr] + bias;
      }
    }
  }
}

// ---------------- carried window output (unswizzle seq frames 256..262) ----------------
__global__ __launch_bounds__(256) void win_out_kernel(
    const short* __restrict__ seqp, float* __restrict__ out)
{
  int idx = blockIdx.x * 256 + threadIdx.x;  // 458752
  int d  = idx & 127;
  int r  = idx >> 7;
  int i  = r % 7;
  int ba = r / 7;
  int f = 256 + i;
  int s = (d >> 3) ^ i;
  out[3932160 + idx] = bf2f(seqp[(ba * SEQ_T + f) * 128 + s * 8 + (d & 7)]);
}

extern "C" void kernel_launch(void* const* d_in, const int* in_sizes, int n_in,
                              void* d_out, int out_size, void* d_ws, size_t ws_size,
                              hipStream_t stream) {
  const float* inp = (const float*)d_in[0];
  const float* hid = (const float*)d_in[1];
  const float* w1  = (const float*)d_in[2];
  const float* b1  = (const float*)d_in[3];
  const float* w2  = (const float*)d_in[4];
  const float* b2  = (const float*)d_in[5];
  const float* w3  = (const float*)d_in[6];
  const float* b3  = (const float*)d_in[7];
  const float* w4  = (const float*)d_in[8];
  const float* b4  = (const float*)d_in[9];
  const float* w5  = (const float*)d_in[10];
  const float* b5  = (const float*)d_in[11];

  char* ws = (char*)d_ws;
  short* wp   = (short*)ws;
  short* w1p  = wp;
  short* w2p  = wp + W2P_OFF;
  short* w3p  = wp + W3P_OFF;
  short* w4p  = wp + W4P_OFF;
  short* w5p  = wp + W5P_OFF;
  short* seqp = (short*)(ws + SEQ_BYTE_OFF);
  short* h3p  = (short*)(ws + BIG_BYTE_OFF);
  float* out  = (float*)d_out;

  pack_w_kernel  <<<WP_TOTAL / 256, 256, 0, stream>>>(w1, w2, w3, w4, w5, wp);
  hid_copy_kernel<<<1792, 256, 0, stream>>>(hid, seqp);
  enc_kernel     <<<2048, 512, 0, stream>>>(inp, w1p, b1, w2p, b2, seqp);
  win_kernel     <<<1024, 512, 0, stream>>>(seqp, w3p, b3, h3p);
  dec_kernel     <<<1024, 512, 0, stream>>>(h3p, w4p, b4, w5p, b5, out);
  win_out_kernel <<<1792, 256, 0, stream>>>(seqp, out);
}